// Round 10
// baseline (3803.338 us; speedup 1.0000x reference)
//
#include <hip/hip_runtime.h>
#include <math.h>

#define T_TOK 2048
#define DDIM 1024
#define HDIM 4096
#define NEXP 8
#define NPRIME 8192            // 2*HDIM interleaved g/v cols per expert
#define KTOT (NEXP * HDIM)     // 32768
#define NSPLIT 8

typedef unsigned short u16;
typedef __attribute__((ext_vector_type(4))) float f32x4;
typedef __attribute__((ext_vector_type(8))) __bf16 bf16x8;
typedef __attribute__((ext_vector_type(8))) unsigned short u16x8;
typedef __attribute__((ext_vector_type(4))) unsigned short u16x4;

__device__ __forceinline__ u16 f2bf(float f) {
  unsigned int u = __builtin_bit_cast(unsigned int, f);
  u += 0x7fffu + ((u >> 16) & 1u);   // round-to-nearest-even
  return (u16)(u >> 16);
}

__device__ __forceinline__ void stage16(const u16* g, u16* l) {
  __builtin_amdgcn_global_load_lds((__attribute__((address_space(1))) void*)g,
                                   (__attribute__((address_space(3))) void*)l,
                                   16, 0, 0);
}

// ---------------- prep: x fp32 -> bf16 ----------------
__global__ void cvt_x_kernel(const float* __restrict__ x, u16* __restrict__ xb) {
  int i = (blockIdx.x * 256 + threadIdx.x) * 8;
  float4 a = *(const float4*)(x + i);
  float4 b = *(const float4*)(x + i + 4);
  u16x8 o;
  o[0] = f2bf(a.x); o[1] = f2bf(a.y); o[2] = f2bf(a.z); o[3] = f2bf(a.w);
  o[4] = f2bf(b.x); o[5] = f2bf(b.y); o[6] = f2bf(b.z); o[7] = f2bf(b.w);
  *(u16x8*)(xb + i) = o;
}

// ---------------- prep: transpose+cvt all experts ----------------
__global__ void transpose_all_kernel(const float* __restrict__ Wg,
                                     const float* __restrict__ Wv,
                                     const float* __restrict__ Wo,
                                     u16* __restrict__ wgvT, u16* __restrict__ woT2) {
  __shared__ float lds[64][65];
  const int bid = blockIdx.x;           // 24576 = 8e * 3mat * 1024 tiles
  const int e = bid / 3072;
  const int r = bid % 3072;
  const int which = r >> 10;            // 0=Wg 1=Wv 2=Wo
  const int tt = r & 1023;
  const float* src; int R, C;
  if (which == 2) { src = Wo + (size_t)e * HDIM * DDIM; R = HDIM; C = DDIM; }
  else            { src = (which ? Wv : Wg) + (size_t)e * DDIM * HDIM; R = DDIM; C = HDIM; }
  const int nrt = R >> 6;
  const int r0 = (tt % nrt) << 6, c0 = (tt / nrt) << 6;
  const int tid = threadIdx.x;
#pragma unroll
  for (int i = 0; i < 4; ++i) {
    int f4 = tid + 256 * i;
    int row = f4 >> 4, c4 = (f4 & 15) << 2;
    float4 v = *(const float4*)(src + (size_t)(r0 + row) * C + c0 + c4);
    lds[row][c4] = v.x; lds[row][c4 + 1] = v.y; lds[row][c4 + 2] = v.z; lds[row][c4 + 3] = v.w;
  }
  __syncthreads();
#pragma unroll
  for (int i = 0; i < 4; ++i) {
    int f4 = tid + 256 * i;
    int cc = f4 >> 4, r4 = (f4 & 15) << 2;
    u16x4 o;
    o[0] = f2bf(lds[r4][cc]);     o[1] = f2bf(lds[r4 + 1][cc]);
    o[2] = f2bf(lds[r4 + 2][cc]); o[3] = f2bf(lds[r4 + 3][cc]);
    u16* dst;
    if (which == 2) {
      dst = woT2 + (size_t)(c0 + cc) * KTOT + e * HDIM + r0 + r4;
    } else {
      int h = c0 + cc;
      int rowp = ((h >> 4) << 5) + which * 16 + (h & 15);
      dst = wgvT + (size_t)e * NPRIME * DDIM + (size_t)rowp * DDIM + r0 + r4;
    }
    *(u16x4*)dst = o;
  }
}

// =================================================================
// GEMM core: BM=256, BN=256, BK=64, 8 waves (2M x 4N), wave tile 128x64.
// R10: SINGLE 64 KB LDS slot (A 32KB + B 32KB) -> 2 blocks/CU resident.
// In-place quarter replacement: stage tile t+1 quarters into the regions
// of tile t that died at the previous post-MFMA barrier:
//   p1: A-h0 + B-nh01 (t+1)   [dead since p0-post]
//   p2: B-nh23 (t+1)          [dead since p1-post]
//   p3: A-h1 (t+1)            [dead since p2-post]
// vmcnt ledger (queue after issue -> wait -> drains):
//   p0: q=4  vmcnt(2) -> B-nh23(t)        [staged p2(t-1)]
//   p1: q=6  vmcnt(4) -> A-h1(t)          [staged p3(t-1)]
//   p2: none
//   p3: q=8  vmcnt(4) -> A-h0,B-nh01(t+1) [staged p1(t)]
// Every wait precedes its barrier (collective visibility); issue->drain
// >= 4 phases. Tail: tp1 clamps to NT-1 (same-address re-stage, value-
// identical => race-free; counts stay uniform). Cross-block overlap is
// the point: block B's MFMA hides block A's read-bursts + prologue +
// epilogue (the R9 diagnosis: lockstep phases serialize LDS and MFMA
// pipes within one block; a co-resident block fills the gaps).
// =================================================================

template<int KS>
__device__ __forceinline__ void gemm_loop(const u16* Ab, const u16* Bb,
                                          int Am0, int Bn0, int kbase, int NT,
                                          u16* lds, int tid, f32x4 (&acc)[8][4]) {
  const int lane = tid & 63;
  const int wave = tid >> 6;
  const int wm = wave >> 2, wn = wave & 3;
  const int l15 = lane & 15, lkq = lane >> 4;

  // ---- staging descriptors (per thread: 2 chunks per quarter-unit)
  const int sl = tid & 7, rw = tid >> 3;          // rw 0..63
  const int slx = (sl ^ (rw & 7)) << 3;           // inverse-swizzled k-offset
  const int rb = (rw & 31) + ((rw >> 5) << 6);    // B base row
  const u16* pA = Ab + (size_t)(Am0 + rw) * KS + kbase + slx;
  const u16* pB = Bb + (size_t)(Bn0 + rb) * KS + kbase + slx;
  const int dA = rw * 64 + sl * 8;
  const int dB = 16384 + rb * 64 + sl * 8;

  auto SA0 = [&](int t) { const int k = t << 6;     // A rows {0-63,128-191}
    stage16(pA + k, lds + dA);
    stage16(pA + (size_t)128 * KS + k, lds + dA + 8192); };
  auto SA1 = [&](int t) { const int k = t << 6;     // A rows {64-127,192-255}
    stage16(pA + (size_t)64 * KS + k, lds + dA + 4096);
    stage16(pA + (size_t)192 * KS + k, lds + dA + 12288); };
  auto SB01 = [&](int t) { const int k = t << 6;    // B rows {x*64+0..31}
    stage16(pB + k, lds + dB);
    stage16(pB + (size_t)128 * KS + k, lds + dB + 8192); };
  auto SB23 = [&](int t) { const int k = t << 6;    // B rows {x*64+32..63}
    stage16(pB + (size_t)32 * KS + k, lds + dB + 2048);
    stage16(pB + (size_t)160 * KS + k, lds + dB + 10240); };

  // ---- strength-reduced read bases (elems). row&7 == l15&7 for all reads.
  const int swz0 = (lkq ^ (l15 & 7)) << 3;        // ks=0 slot
  const int swz1 = ((4 | lkq) ^ (l15 & 7)) << 3;  // ks=1 slot
  const int arow = (wm * 128 + l15) * 64;
  const int brow = 16384 + (wn * 64 + l15) * 64;
  const int a0 = arow + swz0, a1 = arow + swz1;
  const int b0 = brow + swz0, b1 = brow + swz1;

  // prologue: tile 0 fully staged, full drain (once per kernel)
  SA0(0); SB01(0); SB23(0); SA1(0);
  asm volatile("s_waitcnt vmcnt(0)" ::: "memory");
  __builtin_amdgcn_s_barrier();

#pragma unroll 1
  for (int t = 0; t < NT; ++t) {
    const int tp1 = (t + 1 < NT) ? t + 1 : NT - 1;   // clamp keeps counts uniform
    bf16x8 af[4][2], bfr[4][2];

    // ---------- phase 0: read A-h0 + B-nh01 ; vmcnt(2) [B-nh23(t)] ; MFMA m0-3 x n0-1
#pragma unroll
    for (int mf = 0; mf < 4; ++mf) {
      af[mf][0] = *(const bf16x8*)(lds + a0 + mf * 1024);
      af[mf][1] = *(const bf16x8*)(lds + a1 + mf * 1024);
    }
#pragma unroll
    for (int nf = 0; nf < 2; ++nf) {
      bfr[nf][0] = *(const bf16x8*)(lds + b0 + nf * 1024);
      bfr[nf][1] = *(const bf16x8*)(lds + b1 + nf * 1024);
    }
    asm volatile("s_waitcnt vmcnt(2)" ::: "memory");
    __builtin_amdgcn_s_barrier();
    asm volatile("s_waitcnt lgkmcnt(0)" ::: "memory");
    __builtin_amdgcn_sched_barrier(0);
    __builtin_amdgcn_s_setprio(1);
#pragma unroll
    for (int ks = 0; ks < 2; ++ks)
#pragma unroll
      for (int mf = 0; mf < 4; ++mf)
#pragma unroll
        for (int nf = 0; nf < 2; ++nf)
          acc[mf][nf] = __builtin_amdgcn_mfma_f32_16x16x32_bf16(af[mf][ks], bfr[nf][ks], acc[mf][nf], 0, 0, 0);
    __builtin_amdgcn_s_setprio(0);
    __builtin_amdgcn_s_barrier();

    // ---------- phase 1: read B-nh23 ; stage A-h0,B-nh01(t+1) ; vmcnt(4) [A-h1(t)] ; MFMA m0-3 x n2-3
#pragma unroll
    for (int nf = 2; nf < 4; ++nf) {
      bfr[nf][0] = *(const bf16x8*)(lds + b0 + nf * 1024);
      bfr[nf][1] = *(const bf16x8*)(lds + b1 + nf * 1024);
    }
    SA0(tp1); SB01(tp1);
    asm volatile("s_waitcnt vmcnt(4)" ::: "memory");
    __builtin_amdgcn_s_barrier();
    asm volatile("s_waitcnt lgkmcnt(0)" ::: "memory");
    __builtin_amdgcn_sched_barrier(0);
    __builtin_amdgcn_s_setprio(1);
#pragma unroll
    for (int ks = 0; ks < 2; ++ks)
#pragma unroll
      for (int mf = 0; mf < 4; ++mf)
#pragma unroll
        for (int nf = 2; nf < 4; ++nf)
          acc[mf][nf] = __builtin_amdgcn_mfma_f32_16x16x32_bf16(af[mf][ks], bfr[nf][ks], acc[mf][nf], 0, 0, 0);
    __builtin_amdgcn_s_setprio(0);
    __builtin_amdgcn_s_barrier();

    // ---------- phase 2: read A-h1 ; stage B-nh23(t+1) ; MFMA m4-7 x n0-1
#pragma unroll
    for (int mf = 0; mf < 4; ++mf) {
      af[mf][0] = *(const bf16x8*)(lds + a0 + 4096 + mf * 1024);
      af[mf][1] = *(const bf16x8*)(lds + a1 + 4096 + mf * 1024);
    }
    SB23(tp1);
    __builtin_amdgcn_s_barrier();
    asm volatile("s_waitcnt lgkmcnt(0)" ::: "memory");
    __builtin_amdgcn_sched_barrier(0);
    __builtin_amdgcn_s_setprio(1);
#pragma unroll
    for (int ks = 0; ks < 2; ++ks)
#pragma unroll
      for (int mf = 0; mf < 4; ++mf)
#pragma unroll
        for (int nf = 0; nf < 2; ++nf)
          acc[4 + mf][nf] = __builtin_amdgcn_mfma_f32_16x16x32_bf16(af[mf][ks], bfr[nf][ks], acc[4 + mf][nf], 0, 0, 0);
    __builtin_amdgcn_s_setprio(0);
    __builtin_amdgcn_s_barrier();

    // ---------- phase 3: stage A-h1(t+1) ; vmcnt(4) [A-h0,B-nh01(t+1)] ; MFMA m4-7 x n2-3
    SA1(tp1);
    asm volatile("s_waitcnt vmcnt(4)" ::: "memory");
    __builtin_amdgcn_s_barrier();
    __builtin_amdgcn_s_setprio(1);
#pragma unroll
    for (int ks = 0; ks < 2; ++ks)
#pragma unroll
      for (int mf = 0; mf < 4; ++mf)
#pragma unroll
        for (int nf = 2; nf < 4; ++nf)
          acc[4 + mf][nf] = __builtin_amdgcn_mfma_f32_16x16x32_bf16(af[mf][ks], bfr[nf][ks], acc[4 + mf][nf], 0, 0, 0);
    __builtin_amdgcn_s_setprio(0);
    __builtin_amdgcn_s_barrier();
  }
}

// ---------------- GEMM A: h = (gelu(x@Wg) * (x@Wv)) * scale * cw ----------------
__global__ void __launch_bounds__(512, 4)
gemm_gv_kernel(const u16* __restrict__ xb, const u16* __restrict__ wgvT,
               const float* __restrict__ disp, const float* __restrict__ comb,
               const float* __restrict__ scale, u16* __restrict__ h) {
  __shared__ u16 lds[32768];   // 64 KB -> 2 blocks/CU

  // XCD swizzle: 2048 wgs, expert e -> XCD e
  const int bid = blockIdx.x;
  const int wg = (bid & 7) * 256 + (bid >> 3);
  const int e  = wg >> 8;
  const int rr = wg & 255;
  const int nt = rr >> 3;          // 0..31 (N' tiles of 256)
  const int mt = rr & 7;           // 0..7  (M tiles of 256)

  const int tid = threadIdx.x;
  const int lane = tid & 63;
  const int wave = tid >> 6;
  const int wm = wave >> 2, wn = wave & 3;
  const int l15 = lane & 15, lkq = lane >> 4;

  const u16* Bb = wgvT + (size_t)e * NPRIME * DDIM;
  const int Am0 = mt * 256;
  const int Bn0 = nt * 256;

  f32x4 acc[8][4] = {};
  gemm_loop<DDIM>(xb, Bb, Am0, Bn0, 0, DDIM / 64, lds, tid, acc);

  const float s_e = scale[e];
  const int hbase = nt * 128 + wn * 32;   // H-col base within expert
#pragma unroll
  for (int a = 0; a < 8; ++a) {
#pragma unroll
    for (int r = 0; r < 4; ++r) {
      const int t = Am0 + wm * 128 + a * 16 + lkq * 4 + r;
      const float dv = disp[t * NEXP + e];
      const float cv = comb[t * NEXP + e];
      const float s = (dv > 0.0f) ? cv * s_e : 0.0f;
#pragma unroll
      for (int jj = 0; jj < 2; ++jj) {
        const float g = acc[a][2 * jj][r];
        const float v = acc[a][2 * jj + 1][r];
        const float ge = 0.5f * g * (1.0f + erff(g * 0.70710678f));
        h[(size_t)t * KTOT + e * HDIM + hbase + jj * 16 + l15] = f2bf(ge * v * s);
      }
    }
  }
}

// ---------------- GEMM B: P[kz] = h[T][EH] @ woT2[D][EH]^T (split-K 8) ----------------
__global__ void __launch_bounds__(512, 4)
gemm_out_kernel(const u16* __restrict__ hb, const u16* __restrict__ woT2,
                float* __restrict__ P) {
  __shared__ u16 lds[32768];

  const int bid = blockIdx.x;          // 256 wgs
  const int wg = (bid & 7) * 32 + (bid >> 3);
  const int kz = wg >> 5;              // 0..7, one per XCD
  const int rr = wg & 31;
  const int nt = rr >> 3;              // 0..3 (D tiles of 256)
  const int mt = rr & 7;               // 0..7 (token tiles of 256)

  const int tid = threadIdx.x;
  const int lane = tid & 63;
  const int wave = tid >> 6;
  const int wm = wave >> 2, wn = wave & 3;
  const int l15 = lane & 15, lkq = lane >> 4;

  const int Am0 = mt * 256;
  const int Bn0 = nt * 256;
  const int kbase = kz * (KTOT / NSPLIT);   // 4096 per split

  f32x4 acc[8][4] = {};
  gemm_loop<KTOT>(hb, woT2, Am0, Bn0, kbase, (KTOT / NSPLIT) / 64, lds, tid, acc);

  float* Pp = P + (size_t)kz * (T_TOK * DDIM);
#pragma unroll
  for (int a = 0; a < 8; ++a) {
#pragma unroll
    for (int r = 0; r < 4; ++r) {
      const int t = Am0 + wm * 128 + a * 16 + lkq * 4 + r;
#pragma unroll
      for (int nf = 0; nf < 4; ++nf)
        Pp[(size_t)t * DDIM + Bn0 + wn * 64 + nf * 16 + l15] = acc[a][nf][r];
    }
  }
}

// ---------------- final: out = sum of NSPLIT partials ----------------
__global__ void reduce_out_kernel(const float* __restrict__ P, float* __restrict__ out) {
  int i = blockIdx.x * 256 + threadIdx.x;
  float4 a = ((const float4*)P)[i];
#pragma unroll
  for (int s = 1; s < NSPLIT; ++s) {
    float4 b = ((const float4*)P)[i + s * (T_TOK * DDIM / 4)];
    a.x += b.x; a.y += b.y; a.z += b.z; a.w += b.w;
  }
  ((float4*)out)[i] = a;
}

extern "C" void kernel_launch(void* const* d_in, const int* in_sizes, int n_in,
                              void* d_out, int out_size, void* d_ws, size_t ws_size,
                              hipStream_t stream) {
  const float* tokens = (const float*)d_in[0];
  const float* disp   = (const float*)d_in[1];
  const float* comb   = (const float*)d_in[2];
  const float* Wg     = (const float*)d_in[3];
  const float* Wv     = (const float*)d_in[4];
  const float* Wo     = (const float*)d_in[5];
  const float* scale  = (const float*)d_in[6];
  float* out = (float*)d_out;

  char* ws = (char*)d_ws;
  const size_t MB = 1024 * 1024;
  u16* xb    = (u16*)(ws);              // 4 MB   [T][D] bf16
  u16* wgvT  = (u16*)(ws + 4   * MB);   // 128 MB [E][8192][D] interleaved g/v
  u16* woT2  = (u16*)(ws + 132 * MB);   // 64 MB  [D][E*H]
  u16* hbuf  = (u16*)(ws + 196 * MB);   // 128 MB [T][E*H]
  float* P   = (float*)(ws + 324 * MB); // 64 MB  NSPLIT x [T][D] fp32

  cvt_x_kernel<<<1024, 256, 0, stream>>>(tokens, xb);
  transpose_all_kernel<<<24576, 256, 0, stream>>>(Wg, Wv, Wo, wgvT, woT2);
  gemm_gv_kernel<<<2048, 512, 0, stream>>>(xb, wgvT, disp, comb, scale, hbuf);
  gemm_out_kernel<<<256, 512, 0, stream>>>(hbuf, woT2, P);
  reduce_out_kernel<<<2048, 256, 0, stream>>>(P, out);
}

// Round 11
// 876.107 us; speedup vs baseline: 4.3412x; 4.3412x over previous
//
#include <hip/hip_runtime.h>
#include <math.h>

#define T_TOK 2048
#define DDIM 1024
#define HDIM 4096
#define NEXP 8
#define NPRIME 8192            // 2*HDIM interleaved g/v cols per expert
#define KTOT (NEXP * HDIM)     // 32768
#define NSPLIT 8

typedef unsigned short u16;
typedef __attribute__((ext_vector_type(4))) float f32x4;
typedef __attribute__((ext_vector_type(8))) __bf16 bf16x8;
typedef __attribute__((ext_vector_type(8))) unsigned short u16x8;
typedef __attribute__((ext_vector_type(4))) unsigned short u16x4;

__device__ __forceinline__ u16 f2bf(float f) {
  unsigned int u = __builtin_bit_cast(unsigned int, f);
  u += 0x7fffu + ((u >> 16) & 1u);   // round-to-nearest-even
  return (u16)(u >> 16);
}

__device__ __forceinline__ void stage16(const u16* g, u16* l) {
  __builtin_amdgcn_global_load_lds((__attribute__((address_space(1))) void*)g,
                                   (__attribute__((address_space(3))) void*)l,
                                   16, 0, 0);
}

// ---------------- prep: x fp32 -> bf16 ----------------
__global__ void cvt_x_kernel(const float* __restrict__ x, u16* __restrict__ xb) {
  int i = (blockIdx.x * 256 + threadIdx.x) * 8;
  float4 a = *(const float4*)(x + i);
  float4 b = *(const float4*)(x + i + 4);
  u16x8 o;
  o[0] = f2bf(a.x); o[1] = f2bf(a.y); o[2] = f2bf(a.z); o[3] = f2bf(a.w);
  o[4] = f2bf(b.x); o[5] = f2bf(b.y); o[6] = f2bf(b.z); o[7] = f2bf(b.w);
  *(u16x8*)(xb + i) = o;
}

// ---------------- prep: transpose+cvt all experts ----------------
__global__ void transpose_all_kernel(const float* __restrict__ Wg,
                                     const float* __restrict__ Wv,
                                     const float* __restrict__ Wo,
                                     u16* __restrict__ wgvT, u16* __restrict__ woT2) {
  __shared__ float lds[64][65];
  const int bid = blockIdx.x;           // 24576 = 8e * 3mat * 1024 tiles
  const int e = bid / 3072;
  const int r = bid % 3072;
  const int which = r >> 10;            // 0=Wg 1=Wv 2=Wo
  const int tt = r & 1023;
  const float* src; int R, C;
  if (which == 2) { src = Wo + (size_t)e * HDIM * DDIM; R = HDIM; C = DDIM; }
  else            { src = (which ? Wv : Wg) + (size_t)e * DDIM * HDIM; R = DDIM; C = HDIM; }
  const int nrt = R >> 6;
  const int r0 = (tt % nrt) << 6, c0 = (tt / nrt) << 6;
  const int tid = threadIdx.x;
#pragma unroll
  for (int i = 0; i < 4; ++i) {
    int f4 = tid + 256 * i;
    int row = f4 >> 4, c4 = (f4 & 15) << 2;
    float4 v = *(const float4*)(src + (size_t)(r0 + row) * C + c0 + c4);
    lds[row][c4] = v.x; lds[row][c4 + 1] = v.y; lds[row][c4 + 2] = v.z; lds[row][c4 + 3] = v.w;
  }
  __syncthreads();
#pragma unroll
  for (int i = 0; i < 4; ++i) {
    int f4 = tid + 256 * i;
    int cc = f4 >> 4, r4 = (f4 & 15) << 2;
    u16x4 o;
    o[0] = f2bf(lds[r4][cc]);     o[1] = f2bf(lds[r4 + 1][cc]);
    o[2] = f2bf(lds[r4 + 2][cc]); o[3] = f2bf(lds[r4 + 3][cc]);
    u16* dst;
    if (which == 2) {
      dst = woT2 + (size_t)(c0 + cc) * KTOT + e * HDIM + r0 + r4;
    } else {
      int h = c0 + cc;
      int rowp = ((h >> 4) << 5) + which * 16 + (h & 15);
      dst = wgvT + (size_t)e * NPRIME * DDIM + (size_t)rowp * DDIM + r0 + r4;
    }
    *(u16x4*)dst = o;
  }
}

// =================================================================
// gemm_gv (R11): BM=256, BN=256, BK=64, 8 waves (2M x 4N), 128x64/wave.
// A (= xb, 4 MB, L2-resident) is read DIRECTLY from global into regs,
// prefetched one K-tile ahead into the same registers right after their
// last use (af03 after p1, af47 after p3) -> no double-buffer, compiler
// inserts exact counted vmcnt before each use. LDS carries ONLY B
// (2 x 32 KB double buffer). Per-K-tile LDS read 192->64 KB. ONE barrier
// per K-tile: slot-t reads all precede it; SB(t+2) writes all follow it.
// Manual sync ledger (queue at end-of-tile, oldest first):
//   SB(t+1)4 , A03(t+1)8 , A47(t+1)8  = 20  ->  vmcnt(16) drains SB.
// Uniform every tile (tp1 clamps at NT-1: value-identical re-stage).
// =================================================================
__global__ void __launch_bounds__(512, 2)
gemm_gv_kernel(const u16* __restrict__ xb, const u16* __restrict__ wgvT,
               const float* __restrict__ disp, const float* __restrict__ comb,
               const float* __restrict__ scale, u16* __restrict__ h) {
  __shared__ u16 lds[32768];   // 2 slots x 256x64 B-tile (64 KB)

  // XCD swizzle: 2048 wgs, expert e -> XCD e
  const int bid = blockIdx.x;
  const int wg = (bid & 7) * 256 + (bid >> 3);
  const int e  = wg >> 8;
  const int rr = wg & 255;
  const int nt = rr >> 3;          // 0..31 (N' tiles of 256)
  const int mt = rr & 7;           // 0..7  (M tiles of 256)

  const int tid = threadIdx.x;
  const int lane = tid & 63;
  const int wave = tid >> 6;
  const int wm = wave >> 2, wn = wave & 3;
  const int l15 = lane & 15, lkq = lane >> 4;

  const u16* Bb = wgvT + (size_t)e * NPRIME * DDIM;
  const int Am0 = mt * 256;
  const int Bn0 = nt * 256;

  // ---- B staging descriptors (4 chunks/thread per tile)
  const u16* pB[4]; int dB[4];
#pragma unroll
  for (int i = 0; i < 4; ++i) {
    int c = tid + 512 * i, row = c >> 3, sl2 = c & 7;
    pB[i] = Bb + (size_t)(Bn0 + row) * DDIM + ((sl2 ^ (row & 7)) << 3);
    dB[i] = row * 64 + sl2 * 8;
  }
  // ---- B read bases (strength-reduced; row&7 == l15&7)
  const int b0 = (wn * 64 + l15) * 64 + ((lkq ^ (l15 & 7)) << 3);
  const int b1 = (wn * 64 + l15) * 64 + (((4 | lkq) ^ (l15 & 7)) << 3);
  // ---- A direct-global per-lane base
  const u16* pAl = xb + (size_t)(Am0 + wm * 128 + l15) * DDIM + lkq * 8;

  f32x4 acc[8][4] = {};
  bf16x8 af[8][2], bfr[4][2];
  const int NT = DDIM / 64;   // 16

  // prologue: SB(0) -> slot0; A(0) all 16 frags; drain SB only (vmcnt(16))
#pragma unroll
  for (int i = 0; i < 4; ++i) stage16(pB[i], lds + dB[i]);
#pragma unroll
  for (int mf = 0; mf < 8; ++mf) {
    af[mf][0] = *(const bf16x8*)(pAl + mf * 16 * DDIM);
    af[mf][1] = *(const bf16x8*)(pAl + mf * 16 * DDIM + 32);
  }
  asm volatile("s_waitcnt vmcnt(16)" ::: "memory");
  __builtin_amdgcn_s_barrier();

#pragma unroll 1
  for (int t = 0; t < NT; ++t) {
    const u16* sB = lds + (t & 1) * 16384;
    u16* sBn = lds + ((t & 1) ^ 1) * 16384;
    const int tp1 = (t + 1 < NT) ? t + 1 : NT - 1;
    const int kn = tp1 << 6;

    // ---- p0: read B nh01 ; stage SB(t+1) ; MFMA m0-3 x n01
#pragma unroll
    for (int nf = 0; nf < 2; ++nf) {
      bfr[nf][0] = *(const bf16x8*)(sB + b0 + nf * 1024);
      bfr[nf][1] = *(const bf16x8*)(sB + b1 + nf * 1024);
    }
#pragma unroll
    for (int i = 0; i < 4; ++i) stage16(pB[i] + kn, sBn + dB[i]);
    __builtin_amdgcn_sched_barrier(0);
    __builtin_amdgcn_s_setprio(1);
#pragma unroll
    for (int ks = 0; ks < 2; ++ks)
#pragma unroll
      for (int mf = 0; mf < 4; ++mf)
#pragma unroll
        for (int nf = 0; nf < 2; ++nf)
          acc[mf][nf] = __builtin_amdgcn_mfma_f32_16x16x32_bf16(af[mf][ks], bfr[nf][ks], acc[mf][nf], 0, 0, 0);
    __builtin_amdgcn_s_setprio(0);

    // ---- p1: read B nh23 ; MFMA m0-3 x n23 ; then prefetch A03(t+1)
#pragma unroll
    for (int nf = 2; nf < 4; ++nf) {
      bfr[nf][0] = *(const bf16x8*)(sB + b0 + nf * 1024);
      bfr[nf][1] = *(const bf16x8*)(sB + b1 + nf * 1024);
    }
    __builtin_amdgcn_s_setprio(1);
#pragma unroll
    for (int ks = 0; ks < 2; ++ks)
#pragma unroll
      for (int mf = 0; mf < 4; ++mf)
#pragma unroll
        for (int nf = 2; nf < 4; ++nf)
          acc[mf][nf] = __builtin_amdgcn_mfma_f32_16x16x32_bf16(af[mf][ks], bfr[nf][ks], acc[mf][nf], 0, 0, 0);
    __builtin_amdgcn_s_setprio(0);
    __builtin_amdgcn_sched_barrier(0);
#pragma unroll
    for (int mf = 0; mf < 4; ++mf) {
      af[mf][0] = *(const bf16x8*)(pAl + mf * 16 * DDIM + kn);
      af[mf][1] = *(const bf16x8*)(pAl + mf * 16 * DDIM + kn + 32);
    }
    __builtin_amdgcn_sched_barrier(0);

    // ---- p2: MFMA m4-7 x n01
    __builtin_amdgcn_s_setprio(1);
#pragma unroll
    for (int ks = 0; ks < 2; ++ks)
#pragma unroll
      for (int mf = 0; mf < 4; ++mf)
#pragma unroll
        for (int nf = 0; nf < 2; ++nf)
          acc[4 + mf][nf] = __builtin_amdgcn_mfma_f32_16x16x32_bf16(af[4 + mf][ks], bfr[nf][ks], acc[4 + mf][nf], 0, 0, 0);
    __builtin_amdgcn_s_setprio(0);

    // ---- p3: MFMA m4-7 x n23 ; prefetch A47(t+1) ; vmcnt(16) ; barrier
    __builtin_amdgcn_s_setprio(1);
#pragma unroll
    for (int ks = 0; ks < 2; ++ks)
#pragma unroll
      for (int mf = 0; mf < 4; ++mf)
#pragma unroll
        for (int nf = 2; nf < 4; ++nf)
          acc[4 + mf][nf] = __builtin_amdgcn_mfma_f32_16x16x32_bf16(af[4 + mf][ks], bfr[nf][ks], acc[4 + mf][nf], 0, 0, 0);
    __builtin_amdgcn_s_setprio(0);
    __builtin_amdgcn_sched_barrier(0);
#pragma unroll
    for (int mf = 4; mf < 8; ++mf) {
      af[mf][0] = *(const bf16x8*)(pAl + mf * 16 * DDIM + kn);
      af[mf][1] = *(const bf16x8*)(pAl + mf * 16 * DDIM + kn + 32);
    }
    __builtin_amdgcn_sched_barrier(0);
    asm volatile("s_waitcnt vmcnt(16)" ::: "memory");   // drain SB(t+1)
    __builtin_amdgcn_s_barrier();
  }

  const float s_e = scale[e];
  const int hbase = nt * 128 + wn * 32;   // H-col base within expert
#pragma unroll
  for (int a = 0; a < 8; ++a) {
#pragma unroll
    for (int r = 0; r < 4; ++r) {
      const int t = Am0 + wm * 128 + a * 16 + lkq * 4 + r;
      const float dv = disp[t * NEXP + e];
      const float cv = comb[t * NEXP + e];
      const float s = (dv > 0.0f) ? cv * s_e : 0.0f;
#pragma unroll
      for (int jj = 0; jj < 2; ++jj) {
        const float g = acc[a][2 * jj][r];
        const float v = acc[a][2 * jj + 1][r];
        const float ge = 0.5f * g * (1.0f + erff(g * 0.70710678f));
        h[(size_t)t * KTOT + e * HDIM + hbase + jj * 16 + l15] = f2bf(ge * v * s);
      }
    }
  }
}

// =================================================================
// gemm_out: R9 proven loop (2 slots, quarter-replacement, vmcnt(10)).
// =================================================================
template<int KS>
__device__ __forceinline__ void gemm_loop(const u16* Ab, const u16* Bb,
                                          int Am0, int Bn0, int kbase, int NT,
                                          u16* lds, int tid, f32x4 (&acc)[8][4]) {
  const int lane = tid & 63;
  const int wave = tid >> 6;
  const int wm = wave >> 2, wn = wave & 3;
  const int l15 = lane & 15, lkq = lane >> 4;

  const int sl = tid & 7, rw = tid >> 3;
  const int slx = (sl ^ (rw & 7)) << 3;
  const int rb = (rw & 31) + ((rw >> 5) << 6);
  const u16* pA = Ab + (size_t)(Am0 + rw) * KS + kbase + slx;
  const u16* pB = Bb + (size_t)(Bn0 + rb) * KS + kbase + slx;
  const int dA = rw * 64 + sl * 8;
  const int dB = 16384 + rb * 64 + sl * 8;

  auto slot = [&](int t) -> u16* { return lds + (t & 1) * 32768; };
  auto SA0 = [&](int t) { u16* sp = slot(t); const int k = t << 6;
    stage16(pA + k, sp + dA);
    stage16(pA + (size_t)128 * KS + k, sp + dA + 8192); };
  auto SA1 = [&](int t) { u16* sp = slot(t); const int k = t << 6;
    stage16(pA + (size_t)64 * KS + k, sp + dA + 4096);
    stage16(pA + (size_t)192 * KS + k, sp + dA + 12288); };
  auto SB0 = [&](int t) { u16* sp = slot(t); const int k = t << 6;
    stage16(pB + k, sp + dB);
    stage16(pB + (size_t)128 * KS + k, sp + dB + 8192); };
  auto SB1 = [&](int t) { u16* sp = slot(t); const int k = t << 6;
    stage16(pB + (size_t)32 * KS + k, sp + dB + 2048);
    stage16(pB + (size_t)160 * KS + k, sp + dB + 10240); };

  const int swz0 = (lkq ^ (l15 & 7)) << 3;
  const int swz1 = ((4 | lkq) ^ (l15 & 7)) << 3;
  const int arow = (wm * 128 + l15) * 64;
  const int brow = 16384 + (wn * 64 + l15) * 64;
  const int a0 = arow + swz0, a1 = arow + swz1;
  const int b0 = brow + swz0, b1 = brow + swz1;

  SA0(0); SB0(0); SB1(0); SA1(0);
  SA0(1); SB0(1); SB1(1);
  asm volatile("s_waitcnt vmcnt(10)" ::: "memory");
  __builtin_amdgcn_s_barrier();

#pragma unroll 1
  for (int t = 0; t < NT; ++t) {
    const u16* s = slot(t);
    const int tp1 = (t + 1 < NT) ? t + 1 : NT - 1;
    const int tp2 = (t + 2 < NT) ? t + 2 : NT - 1;
    bf16x8 af[4][2], bfr[4][2];

#pragma unroll
    for (int mf = 0; mf < 4; ++mf) {
      af[mf][0] = *(const bf16x8*)(s + a0 + mf * 1024);
      af[mf][1] = *(const bf16x8*)(s + a1 + mf * 1024);
    }
#pragma unroll
    for (int nf = 0; nf < 2; ++nf) {
      bfr[nf][0] = *(const bf16x8*)(s + b0 + nf * 1024);
      bfr[nf][1] = *(const bf16x8*)(s + b1 + nf * 1024);
    }
    SA1(tp1);
    asm volatile("s_waitcnt vmcnt(10)" ::: "memory");
    __builtin_amdgcn_s_barrier();
    asm volatile("s_waitcnt lgkmcnt(0)" ::: "memory");
    __builtin_amdgcn_sched_barrier(0);
    __builtin_amdgcn_s_setprio(1);
#pragma unroll
    for (int ks = 0; ks < 2; ++ks)
#pragma unroll
      for (int mf = 0; mf < 4; ++mf)
#pragma unroll
        for (int nf = 0; nf < 2; ++nf)
          acc[mf][nf] = __builtin_amdgcn_mfma_f32_16x16x32_bf16(af[mf][ks], bfr[nf][ks], acc[mf][nf], 0, 0, 0);
    __builtin_amdgcn_s_setprio(0);
    __builtin_amdgcn_s_barrier();

#pragma unroll
    for (int nf = 2; nf < 4; ++nf) {
      bfr[nf][0] = *(const bf16x8*)(s + b0 + nf * 1024);
      bfr[nf][1] = *(const bf16x8*)(s + b1 + nf * 1024);
    }
    SA0(tp2);
    asm volatile("s_waitcnt vmcnt(10)" ::: "memory");
    __builtin_amdgcn_s_barrier();
    asm volatile("s_waitcnt lgkmcnt(0)" ::: "memory");
    __builtin_amdgcn_sched_barrier(0);
    __builtin_amdgcn_s_setprio(1);
#pragma unroll
    for (int ks = 0; ks < 2; ++ks)
#pragma unroll
      for (int mf = 0; mf < 4; ++mf)
#pragma unroll
        for (int nf = 2; nf < 4; ++nf)
          acc[mf][nf] = __builtin_amdgcn_mfma_f32_16x16x32_bf16(af[mf][ks], bfr[nf][ks], acc[mf][nf], 0, 0, 0);
    __builtin_amdgcn_s_setprio(0);
    __builtin_amdgcn_s_barrier();

#pragma unroll
    for (int mf = 0; mf < 4; ++mf) {
      af[mf][0] = *(const bf16x8*)(s + a0 + 4096 + mf * 1024);
      af[mf][1] = *(const bf16x8*)(s + a1 + 4096 + mf * 1024);
    }
    SB0(tp2);
    __builtin_amdgcn_s_barrier();
    asm volatile("s_waitcnt lgkmcnt(0)" ::: "memory");
    __builtin_amdgcn_sched_barrier(0);
    __builtin_amdgcn_s_setprio(1);
#pragma unroll
    for (int ks = 0; ks < 2; ++ks)
#pragma unroll
      for (int mf = 0; mf < 4; ++mf)
#pragma unroll
        for (int nf = 0; nf < 2; ++nf)
          acc[4 + mf][nf] = __builtin_amdgcn_mfma_f32_16x16x32_bf16(af[mf][ks], bfr[nf][ks], acc[4 + mf][nf], 0, 0, 0);
    __builtin_amdgcn_s_setprio(0);
    __builtin_amdgcn_s_barrier();

    SB1(tp2);
    asm volatile("s_waitcnt vmcnt(10)" ::: "memory");
    __builtin_amdgcn_s_barrier();
    __builtin_amdgcn_s_setprio(1);
#pragma unroll
    for (int ks = 0; ks < 2; ++ks)
#pragma unroll
      for (int mf = 0; mf < 4; ++mf)
#pragma unroll
        for (int nf = 2; nf < 4; ++nf)
          acc[4 + mf][nf] = __builtin_amdgcn_mfma_f32_16x16x32_bf16(af[mf][ks], bfr[nf][ks], acc[4 + mf][nf], 0, 0, 0);
    __builtin_amdgcn_s_setprio(0);
    __builtin_amdgcn_s_barrier();
  }
}

// ---------------- GEMM B: P[kz] = h[T][EH] @ woT2[D][EH]^T (split-K 8) ----------------
__global__ void __launch_bounds__(512, 2)
gemm_out_kernel(const u16* __restrict__ hb, const u16* __restrict__ woT2,
                float* __restrict__ P) {
  __shared__ u16 lds[65536];

  const int bid = blockIdx.x;          // 256 wgs
  const int wg = (bid & 7) * 32 + (bid >> 3);
  const int kz = wg >> 5;              // 0..7, one per XCD
  const int rr = wg & 31;
  const int nt = rr >> 3;              // 0..3 (D tiles of 256)
  const int mt = rr & 7;               // 0..7 (token tiles of 256)

  const int tid = threadIdx.x;
  const int lane = tid & 63;
  const int wave = tid >> 6;
  const int wm = wave >> 2, wn = wave & 3;
  const int l15 = lane & 15, lkq = lane >> 4;

  const int Am0 = mt * 256;
  const int Bn0 = nt * 256;
  const int kbase = kz * (KTOT / NSPLIT);   // 4096 per split

  f32x4 acc[8][4] = {};
  gemm_loop<KTOT>(hb, woT2, Am0, Bn0, kbase, (KTOT / NSPLIT) / 64, lds, tid, acc);

  float* Pp = P + (size_t)kz * (T_TOK * DDIM);
#pragma unroll
  for (int a = 0; a < 8; ++a) {
#pragma unroll
    for (int r = 0; r < 4; ++r) {
      const int t = Am0 + wm * 128 + a * 16 + lkq * 4 + r;
#pragma unroll
      for (int nf = 0; nf < 4; ++nf)
        Pp[(size_t)t * DDIM + Bn0 + wn * 64 + nf * 16 + l15] = acc[a][nf][r];
    }
  }
}

// ---------------- final: out = sum of NSPLIT partials ----------------
__global__ void reduce_out_kernel(const float* __restrict__ P, float* __restrict__ out) {
  int i = blockIdx.x * 256 + threadIdx.x;
  float4 a = ((const float4*)P)[i];
#pragma unroll
  for (int s = 1; s < NSPLIT; ++s) {
    float4 b = ((const float4*)P)[i + s * (T_TOK * DDIM / 4)];
    a.x += b.x; a.y += b.y; a.z += b.z; a.w += b.w;
  }
  ((float4*)out)[i] = a;
}

extern "C" void kernel_launch(void* const* d_in, const int* in_sizes, int n_in,
                              void* d_out, int out_size, void* d_ws, size_t ws_size,
                              hipStream_t stream) {
  const float* tokens = (const float*)d_in[0];
  const float* disp   = (const float*)d_in[1];
  const float* comb   = (const float*)d_in[2];
  const float* Wg     = (const float*)d_in[3];
  const float* Wv     = (const float*)d_in[4];
  const float* Wo     = (const float*)d_in[5];
  const float* scale  = (const float*)d_in[6];
  float* out = (float*)d_out;

  char* ws = (char*)d_ws;
  const size_t MB = 1024 * 1024;
  u16* xb    = (u16*)(ws);              // 4 MB   [T][D] bf16
  u16* wgvT  = (u16*)(ws + 4   * MB);   // 128 MB [E][8192][D] interleaved g/v
  u16* woT2  = (u16*)(ws + 132 * MB);   // 64 MB  [D][E*H]
  u16* hbuf  = (u16*)(ws + 196 * MB);   // 128 MB [T][E*H]
  float* P   = (float*)(ws + 324 * MB); // 64 MB  NSPLIT x [T][D] fp32

  cvt_x_kernel<<<1024, 256, 0, stream>>>(tokens, xb);
  transpose_all_kernel<<<24576, 256, 0, stream>>>(Wg, Wv, Wo, wgvT, woT2);
  gemm_gv_kernel<<<2048, 512, 0, stream>>>(xb, wgvT, disp, comb, scale, hbuf);
  gemm_out_kernel<<<256, 512, 0, stream>>>(hbuf, woT2, P);
  reduce_out_kernel<<<2048, 256, 0, stream>>>(P, out);
}

// Round 12
// 566.400 us; speedup vs baseline: 6.7149x; 1.5468x over previous
//
#include <hip/hip_runtime.h>
#include <math.h>

#define T_TOK 2048
#define DDIM 1024
#define HDIM 4096
#define NEXP 8
#define NPRIME 8192            // 2*HDIM interleaved g/v cols per expert
#define KTOT (NEXP * HDIM)     // 32768
#define NSPLIT 8

typedef unsigned short u16;
typedef __attribute__((ext_vector_type(4))) float f32x4;
typedef __attribute__((ext_vector_type(8))) __bf16 bf16x8;
typedef __attribute__((ext_vector_type(8))) unsigned short u16x8;
typedef __attribute__((ext_vector_type(4))) unsigned short u16x4;

__device__ __forceinline__ u16 f2bf(float f) {
  unsigned int u = __builtin_bit_cast(unsigned int, f);
  u += 0x7fffu + ((u >> 16) & 1u);   // round-to-nearest-even
  return (u16)(u >> 16);
}

__device__ __forceinline__ void stage16(const u16* g, u16* l) {
  __builtin_amdgcn_global_load_lds((__attribute__((address_space(1))) void*)g,
                                   (__attribute__((address_space(3))) void*)l,
                                   16, 0, 0);
}

// ---------------- prep: x fp32 -> bf16 ----------------
__global__ void cvt_x_kernel(const float* __restrict__ x, u16* __restrict__ xb) {
  int i = (blockIdx.x * 256 + threadIdx.x) * 8;
  float4 a = *(const float4*)(x + i);
  float4 b = *(const float4*)(x + i + 4);
  u16x8 o;
  o[0] = f2bf(a.x); o[1] = f2bf(a.y); o[2] = f2bf(a.z); o[3] = f2bf(a.w);
  o[4] = f2bf(b.x); o[5] = f2bf(b.y); o[6] = f2bf(b.z); o[7] = f2bf(b.w);
  *(u16x8*)(xb + i) = o;
}

// ---------------- prep: transpose+cvt all experts ----------------
__global__ void transpose_all_kernel(const float* __restrict__ Wg,
                                     const float* __restrict__ Wv,
                                     const float* __restrict__ Wo,
                                     u16* __restrict__ wgvT, u16* __restrict__ woT2) {
  __shared__ float lds[64][65];
  const int bid = blockIdx.x;           // 24576 = 8e * 3mat * 1024 tiles
  const int e = bid / 3072;
  const int r = bid % 3072;
  const int which = r >> 10;            // 0=Wg 1=Wv 2=Wo
  const int tt = r & 1023;
  const float* src; int R, C;
  if (which == 2) { src = Wo + (size_t)e * HDIM * DDIM; R = HDIM; C = DDIM; }
  else            { src = (which ? Wv : Wg) + (size_t)e * DDIM * HDIM; R = DDIM; C = HDIM; }
  const int nrt = R >> 6;
  const int r0 = (tt % nrt) << 6, c0 = (tt / nrt) << 6;
  const int tid = threadIdx.x;
#pragma unroll
  for (int i = 0; i < 4; ++i) {
    int f4 = tid + 256 * i;
    int row = f4 >> 4, c4 = (f4 & 15) << 2;
    float4 v = *(const float4*)(src + (size_t)(r0 + row) * C + c0 + c4);
    lds[row][c4] = v.x; lds[row][c4 + 1] = v.y; lds[row][c4 + 2] = v.z; lds[row][c4 + 3] = v.w;
  }
  __syncthreads();
#pragma unroll
  for (int i = 0; i < 4; ++i) {
    int f4 = tid + 256 * i;
    int cc = f4 >> 4, r4 = (f4 & 15) << 2;
    u16x4 o;
    o[0] = f2bf(lds[r4][cc]);     o[1] = f2bf(lds[r4 + 1][cc]);
    o[2] = f2bf(lds[r4 + 2][cc]); o[3] = f2bf(lds[r4 + 3][cc]);
    u16* dst;
    if (which == 2) {
      dst = woT2 + (size_t)(c0 + cc) * KTOT + e * HDIM + r0 + r4;
    } else {
      int h = c0 + cc;
      int rowp = ((h >> 4) << 5) + which * 16 + (h & 15);
      dst = wgvT + (size_t)e * NPRIME * DDIM + (size_t)rowp * DDIM + r0 + r4;
    }
    *(u16x4*)dst = o;
  }
}

// =================================================================
// GEMM core (R12): BM=256, BN=256, BK=64, 8 waves (2M x 4N), 128x64/wave.
// 2 LDS slots (64 KB each), XOR-8 swizzle, strength-reduced reads.
// MINIMAL SYNC: ONE s_barrier + ONE vmcnt(0) per K-tile. Hazard ledger:
//  - WAR: stage(t+1 -> slot s2) issued during tile t; s2's previous
//    reads (tile t-1) lgkm-drained within tile t-1, separated by the
//    end-of-(t-1) barrier.  One barrier suffices.
//  - RAW: vmcnt(0)+barrier at end of t => tile t+1 resident. Last stage
//    unit issued >=1500 cyc before the wait (covered by L2/HBM latency).
//  - Tail: stage index clamps to NT-1 -> targets the CURRENT slot with
//    value-identical bytes (benign).
// No asm lgkmcnt / sched_barrier pins: compiler emits fine-grained
// lgkmcnt (m97) and can interleave reads/stages/MFMA; waves can slip
// by up to a tile, so one wave's MFMA hides the other's LDS reads.
// =================================================================

template<int KS>
__device__ __forceinline__ void gemm_loop(const u16* Ab, const u16* Bb,
                                          int Am0, int Bn0, int kbase, int NT,
                                          u16* lds, int tid, f32x4 (&acc)[8][4]) {
  const int lane = tid & 63;
  const int wave = tid >> 6;
  const int wm = wave >> 2, wn = wave & 3;
  const int l15 = lane & 15, lkq = lane >> 4;

  // ---- staging descriptors (per thread: 2 chunks per quarter-unit)
  const int sl = tid & 7, rw = tid >> 3;          // rw 0..63
  const int slx = (sl ^ (rw & 7)) << 3;           // inverse-swizzled k-offset
  const int rb = (rw & 31) + ((rw >> 5) << 6);    // B base row
  const u16* pA = Ab + (size_t)(Am0 + rw) * KS + kbase + slx;
  const u16* pB = Bb + (size_t)(Bn0 + rb) * KS + kbase + slx;
  const int dA = rw * 64 + sl * 8;
  const int dB = 16384 + rb * 64 + sl * 8;

  auto slotp = [&](int t) -> u16* { return lds + (t & 1) * 32768; };
  auto SA0 = [&](int t) { u16* sp = slotp(t); const int k = t << 6;
    stage16(pA + k, sp + dA);
    stage16(pA + (size_t)128 * KS + k, sp + dA + 8192); };
  auto SA1 = [&](int t) { u16* sp = slotp(t); const int k = t << 6;
    stage16(pA + (size_t)64 * KS + k, sp + dA + 4096);
    stage16(pA + (size_t)192 * KS + k, sp + dA + 12288); };
  auto SB0 = [&](int t) { u16* sp = slotp(t); const int k = t << 6;
    stage16(pB + k, sp + dB);
    stage16(pB + (size_t)128 * KS + k, sp + dB + 8192); };
  auto SB1 = [&](int t) { u16* sp = slotp(t); const int k = t << 6;
    stage16(pB + (size_t)32 * KS + k, sp + dB + 2048);
    stage16(pB + (size_t)160 * KS + k, sp + dB + 10240); };

  // ---- strength-reduced read bases (elems). row&7 == l15&7 for all reads.
  const int swz0 = (lkq ^ (l15 & 7)) << 3;        // ks=0 slot
  const int swz1 = ((4 | lkq) ^ (l15 & 7)) << 3;  // ks=1 slot
  const int arow = (wm * 128 + l15) * 64;
  const int brow = 16384 + (wn * 64 + l15) * 64;
  const int a0 = arow + swz0, a1 = arow + swz1;
  const int b0 = brow + swz0, b1 = brow + swz1;

  // prologue: tile 0 fully staged, full drain (once per kernel)
  SA0(0); SB0(0); SB1(0); SA1(0);
  asm volatile("s_waitcnt vmcnt(0)" ::: "memory");
  __builtin_amdgcn_s_barrier();

#pragma unroll 1
  for (int t = 0; t < NT; ++t) {
    const u16* s = slotp(t);
    const int tp1 = (t + 1 < NT) ? t + 1 : NT - 1;   // clamp: value-identical re-stage at tail
    bf16x8 af[8], bfr[4];

    // ---- half 1: reads ks=0 ; stage A0,B0(t+1) ; 32 MFMA (ks0)
#pragma unroll
    for (int mf = 0; mf < 8; ++mf) af[mf] = *(const bf16x8*)(s + a0 + mf * 1024);
#pragma unroll
    for (int nf = 0; nf < 4; ++nf) bfr[nf] = *(const bf16x8*)(s + b0 + nf * 1024);
    SA0(tp1); SB0(tp1);
    __builtin_amdgcn_s_setprio(1);
#pragma unroll
    for (int mf = 0; mf < 8; ++mf)
#pragma unroll
      for (int nf = 0; nf < 4; ++nf)
        acc[mf][nf] = __builtin_amdgcn_mfma_f32_16x16x32_bf16(af[mf], bfr[nf], acc[mf][nf], 0, 0, 0);
    __builtin_amdgcn_s_setprio(0);

    // ---- half 2: reads ks=1 ; stage B1,A1(t+1) ; 32 MFMA (ks1)
#pragma unroll
    for (int mf = 0; mf < 8; ++mf) af[mf] = *(const bf16x8*)(s + a1 + mf * 1024);
#pragma unroll
    for (int nf = 0; nf < 4; ++nf) bfr[nf] = *(const bf16x8*)(s + b1 + nf * 1024);
    SB1(tp1); SA1(tp1);
    __builtin_amdgcn_s_setprio(1);
#pragma unroll
    for (int mf = 0; mf < 8; ++mf)
#pragma unroll
      for (int nf = 0; nf < 4; ++nf)
        acc[mf][nf] = __builtin_amdgcn_mfma_f32_16x16x32_bf16(af[mf], bfr[nf], acc[mf][nf], 0, 0, 0);
    __builtin_amdgcn_s_setprio(0);

    // ---- single end-of-tile sync: next tile resident + slot swap safe
    asm volatile("s_waitcnt vmcnt(0)" ::: "memory");
    __builtin_amdgcn_s_barrier();
  }
}

// ---------------- GEMM A: h = (gelu(x@Wg) * (x@Wv)) * scale * cw ----------------
__global__ void __launch_bounds__(512, 2)
gemm_gv_kernel(const u16* __restrict__ xb, const u16* __restrict__ wgvT,
               const float* __restrict__ disp, const float* __restrict__ comb,
               const float* __restrict__ scale, u16* __restrict__ h) {
  __shared__ u16 lds[65536];

  // XCD swizzle: 2048 wgs, expert e -> XCD e
  const int bid = blockIdx.x;
  const int wg = (bid & 7) * 256 + (bid >> 3);
  const int e  = wg >> 8;
  const int rr = wg & 255;
  const int nt = rr >> 3;          // 0..31 (N' tiles of 256)
  const int mt = rr & 7;           // 0..7  (M tiles of 256)

  const int tid = threadIdx.x;
  const int lane = tid & 63;
  const int wave = tid >> 6;
  const int wm = wave >> 2, wn = wave & 3;
  const int l15 = lane & 15, lkq = lane >> 4;

  const u16* Bb = wgvT + (size_t)e * NPRIME * DDIM;
  const int Am0 = mt * 256;
  const int Bn0 = nt * 256;

  f32x4 acc[8][4] = {};
  gemm_loop<DDIM>(xb, Bb, Am0, Bn0, 0, DDIM / 64, lds, tid, acc);

  const float s_e = scale[e];
  const int hbase = nt * 128 + wn * 32;   // H-col base within expert
#pragma unroll
  for (int a = 0; a < 8; ++a) {
#pragma unroll
    for (int r = 0; r < 4; ++r) {
      const int t = Am0 + wm * 128 + a * 16 + lkq * 4 + r;
      const float dv = disp[t * NEXP + e];
      const float cv = comb[t * NEXP + e];
      const float s = (dv > 0.0f) ? cv * s_e : 0.0f;
#pragma unroll
      for (int jj = 0; jj < 2; ++jj) {
        const float g = acc[a][2 * jj][r];
        const float v = acc[a][2 * jj + 1][r];
        const float ge = 0.5f * g * (1.0f + erff(g * 0.70710678f));
        h[(size_t)t * KTOT + e * HDIM + hbase + jj * 16 + l15] = f2bf(ge * v * s);
      }
    }
  }
}

// ---------------- GEMM B: P[kz] = h[T][EH] @ woT2[D][EH]^T (split-K 8) ----------------
__global__ void __launch_bounds__(512, 2)
gemm_out_kernel(const u16* __restrict__ hb, const u16* __restrict__ woT2,
                float* __restrict__ P) {
  __shared__ u16 lds[65536];

  const int bid = blockIdx.x;          // 256 wgs
  const int wg = (bid & 7) * 32 + (bid >> 3);
  const int kz = wg >> 5;              // 0..7, one per XCD
  const int rr = wg & 31;
  const int nt = rr >> 3;              // 0..3 (D tiles of 256)
  const int mt = rr & 7;               // 0..7 (token tiles of 256)

  const int tid = threadIdx.x;
  const int lane = tid & 63;
  const int wave = tid >> 6;
  const int wm = wave >> 2, wn = wave & 3;
  const int l15 = lane & 15, lkq = lane >> 4;

  const int Am0 = mt * 256;
  const int Bn0 = nt * 256;
  const int kbase = kz * (KTOT / NSPLIT);   // 4096 per split

  f32x4 acc[8][4] = {};
  gemm_loop<KTOT>(hb, woT2, Am0, Bn0, kbase, (KTOT / NSPLIT) / 64, lds, tid, acc);

  float* Pp = P + (size_t)kz * (T_TOK * DDIM);
#pragma unroll
  for (int a = 0; a < 8; ++a) {
#pragma unroll
    for (int r = 0; r < 4; ++r) {
      const int t = Am0 + wm * 128 + a * 16 + lkq * 4 + r;
#pragma unroll
      for (int nf = 0; nf < 4; ++nf)
        Pp[(size_t)t * DDIM + Bn0 + wn * 64 + nf * 16 + l15] = acc[a][nf][r];
    }
  }
}

// ---------------- final: out = sum of NSPLIT partials ----------------
__global__ void reduce_out_kernel(const float* __restrict__ P, float* __restrict__ out) {
  int i = blockIdx.x * 256 + threadIdx.x;
  float4 a = ((const float4*)P)[i];
#pragma unroll
  for (int s = 1; s < NSPLIT; ++s) {
    float4 b = ((const float4*)P)[i + s * (T_TOK * DDIM / 4)];
    a.x += b.x; a.y += b.y; a.z += b.z; a.w += b.w;
  }
  ((float4*)out)[i] = a;
}

extern "C" void kernel_launch(void* const* d_in, const int* in_sizes, int n_in,
                              void* d_out, int out_size, void* d_ws, size_t ws_size,
                              hipStream_t stream) {
  const float* tokens = (const float*)d_in[0];
  const float* disp   = (const float*)d_in[1];
  const float* comb   = (const float*)d_in[2];
  const float* Wg     = (const float*)d_in[3];
  const float* Wv     = (const float*)d_in[4];
  const float* Wo     = (const float*)d_in[5];
  const float* scale  = (const float*)d_in[6];
  float* out = (float*)d_out;

  char* ws = (char*)d_ws;
  const size_t MB = 1024 * 1024;
  u16* xb    = (u16*)(ws);              // 4 MB   [T][D] bf16
  u16* wgvT  = (u16*)(ws + 4   * MB);   // 128 MB [E][8192][D] interleaved g/v
  u16* woT2  = (u16*)(ws + 132 * MB);   // 64 MB  [D][E*H]
  u16* hbuf  = (u16*)(ws + 196 * MB);   // 128 MB [T][E*H]
  float* P   = (float*)(ws + 324 * MB); // 64 MB  NSPLIT x [T][D] fp32

  cvt_x_kernel<<<1024, 256, 0, stream>>>(tokens, xb);
  transpose_all_kernel<<<24576, 256, 0, stream>>>(Wg, Wv, Wo, wgvT, woT2);
  gemm_gv_kernel<<<2048, 512, 0, stream>>>(xb, wgvT, disp, comb, scale, hbuf);
  gemm_out_kernel<<<256, 512, 0, stream>>>(hbuf, woT2, P);
  reduce_out_kernel<<<2048, 256, 0, stream>>>(P, out);
}

// Round 13
// 564.040 us; speedup vs baseline: 6.7430x; 1.0042x over previous
//
#include <hip/hip_runtime.h>
#include <math.h>

#define T_TOK 2048
#define DDIM 1024
#define HDIM 4096
#define NEXP 8
#define NPRIME 8192            // 2*HDIM interleaved g/v cols per expert
#define KTOT (NEXP * HDIM)     // 32768
#define NSPLIT 8

typedef unsigned short u16;
typedef __attribute__((ext_vector_type(4))) float f32x4;
typedef __attribute__((ext_vector_type(8))) __bf16 bf16x8;
typedef __attribute__((ext_vector_type(8))) unsigned short u16x8;
typedef __attribute__((ext_vector_type(4))) unsigned short u16x4;

__device__ __forceinline__ u16 f2bf(float f) {
  unsigned int u = __builtin_bit_cast(unsigned int, f);
  u += 0x7fffu + ((u >> 16) & 1u);   // round-to-nearest-even
  return (u16)(u >> 16);
}

__device__ __forceinline__ void stage16(const u16* g, u16* l) {
  __builtin_amdgcn_global_load_lds((__attribute__((address_space(1))) void*)g,
                                   (__attribute__((address_space(3))) void*)l,
                                   16, 0, 0);
}

// ---------------- prep: x fp32 -> bf16 ----------------
__global__ void cvt_x_kernel(const float* __restrict__ x, u16* __restrict__ xb) {
  int i = (blockIdx.x * 256 + threadIdx.x) * 8;
  float4 a = *(const float4*)(x + i);
  float4 b = *(const float4*)(x + i + 4);
  u16x8 o;
  o[0] = f2bf(a.x); o[1] = f2bf(a.y); o[2] = f2bf(a.z); o[3] = f2bf(a.w);
  o[4] = f2bf(b.x); o[5] = f2bf(b.y); o[6] = f2bf(b.z); o[7] = f2bf(b.w);
  *(u16x8*)(xb + i) = o;
}

// ---------------- prep: transpose+cvt all experts ----------------
__global__ void transpose_all_kernel(const float* __restrict__ Wg,
                                     const float* __restrict__ Wv,
                                     const float* __restrict__ Wo,
                                     u16* __restrict__ wgvT, u16* __restrict__ woT2) {
  __shared__ float lds[64][65];
  const int bid = blockIdx.x;           // 24576 = 8e * 3mat * 1024 tiles
  const int e = bid / 3072;
  const int r = bid % 3072;
  const int which = r >> 10;            // 0=Wg 1=Wv 2=Wo
  const int tt = r & 1023;
  const float* src; int R, C;
  if (which == 2) { src = Wo + (size_t)e * HDIM * DDIM; R = HDIM; C = DDIM; }
  else            { src = (which ? Wv : Wg) + (size_t)e * DDIM * HDIM; R = DDIM; C = HDIM; }
  const int nrt = R >> 6;
  const int r0 = (tt % nrt) << 6, c0 = (tt / nrt) << 6;
  const int tid = threadIdx.x;
#pragma unroll
  for (int i = 0; i < 4; ++i) {
    int f4 = tid + 256 * i;
    int row = f4 >> 4, c4 = (f4 & 15) << 2;
    float4 v = *(const float4*)(src + (size_t)(r0 + row) * C + c0 + c4);
    lds[row][c4] = v.x; lds[row][c4 + 1] = v.y; lds[row][c4 + 2] = v.z; lds[row][c4 + 3] = v.w;
  }
  __syncthreads();
#pragma unroll
  for (int i = 0; i < 4; ++i) {
    int f4 = tid + 256 * i;
    int cc = f4 >> 4, r4 = (f4 & 15) << 2;
    u16x4 o;
    o[0] = f2bf(lds[r4][cc]);     o[1] = f2bf(lds[r4 + 1][cc]);
    o[2] = f2bf(lds[r4 + 2][cc]); o[3] = f2bf(lds[r4 + 3][cc]);
    u16* dst;
    if (which == 2) {
      dst = woT2 + (size_t)(c0 + cc) * KTOT + e * HDIM + r0 + r4;
    } else {
      int h = c0 + cc;
      int rowp = ((h >> 4) << 5) + which * 16 + (h & 15);
      dst = wgvT + (size_t)e * NPRIME * DDIM + (size_t)rowp * DDIM + r0 + r4;
    }
    *(u16x4*)dst = o;
  }
}

// =================================================================
// GEMM core (R13): BM=256, BN=128, BK=64, 4 waves (2M x 2N), 128x64/wave,
// 256 threads, LDS 64 KB/block (A single 32 KB slot, B 2x16 KB dbuf)
// -> 2 BLOCKS PER CU. Cross-block desync is the lever: one block's MFMA
// cluster overlaps the other block's reads/stages/prologue/epilogue
// (gemm_out evidence: same loop at 1 long-lived block/CU = 46%;
// gemm_gv's 8 short blocks/CU = 33% -- overhead un-hidden).
// Per K-tile: read A-all(16)+B-ks0(4) ; lgkmcnt(0)+barrier (all reads
// complete before any stage write can land) ; stage A(t+1) IN PLACE +
// B(t+1)->other slot ; 32 MFMA ks0 ; read B-ks1(4) (untouched slot) ;
// 32 MFMA ks1 ; vmcnt(0)+barrier (tile t+1 resident, collective).
// Tail: tp1 clamps to NT-1 (value-identical in-place re-stage, benign).
// XOR-8 swizzle on 128B rows (0 conflicts, verified R4-R12).
// =================================================================

template<int KS>
__device__ __forceinline__ void gemm_loop(const u16* Ab, const u16* Bb,
                                          int Am0, int Bn0, int kbase, int NT,
                                          u16* lds, int tid, f32x4 (&acc)[8][4]) {
  const int lane = tid & 63;
  const int wave = tid >> 6;            // 0..3
  const int wm = wave >> 1, wn = wave & 1;
  const int l15 = lane & 15, lkq = lane >> 4;

  // ---- staging descriptors. chunk c = tid + 256*i -> row = (tid>>3)+32*i,
  // slot sl = tid&7. row&7 invariant of i => swizzle offset constant.
  const int sl = tid & 7, r0 = tid >> 3;          // r0 0..31
  const int slx = (sl ^ (r0 & 7)) << 3;           // inverse-swizzled k-offset
  const u16* pA = Ab + (size_t)(Am0 + r0) * KS + kbase + slx;
  const u16* pB = Bb + (size_t)(Bn0 + r0) * KS + kbase + slx;
  const int dA0 = r0 * 64 + sl * 8;               // + i*2048 per chunk
  const int dB0 = r0 * 64 + sl * 8;               // region-relative

  // ---- strength-reduced read bases (elems). row&7 == l15&7 for all reads.
  const int swz0 = (lkq ^ (l15 & 7)) << 3;        // ks=0 slot
  const int swz1 = ((4 | lkq) ^ (l15 & 7)) << 3;  // ks=1 slot
  const int arow = (wm * 128 + l15) * 64;
  const int brow = (wn * 64 + l15) * 64;          // region-relative
  const int a0 = arow + swz0, a1 = arow + swz1;
  const int b0 = brow + swz0, b1 = brow + swz1;

  // prologue: A(0) + B(0)->slot0, full drain once
#pragma unroll
  for (int i = 0; i < 8; ++i) stage16(pA + (size_t)(i * 32) * KS, lds + dA0 + i * 2048);
#pragma unroll
  for (int i = 0; i < 4; ++i) stage16(pB + (size_t)(i * 32) * KS, lds + 16384 + dB0 + i * 2048);
  asm volatile("s_waitcnt vmcnt(0)" ::: "memory");
  __builtin_amdgcn_s_barrier();

#pragma unroll 1
  for (int t = 0; t < NT; ++t) {
    const int bs = 16384 + ((t & 1) << 13);        // current B slot (elems)
    const int bn = 16384 + (((t + 1) & 1) << 13);  // next B slot
    const int tp1 = (t + 1 < NT) ? t + 1 : NT - 1; // clamp: benign re-stage at tail
    const size_t kn = (size_t)(tp1 << 6);
    bf16x8 af[8][2], bfr[4];

    // ---- read ALL A fragments + B ks=0 (A-slot dies after barrier)
#pragma unroll
    for (int mf = 0; mf < 8; ++mf) {
      af[mf][0] = *(const bf16x8*)(lds + a0 + mf * 1024);
      af[mf][1] = *(const bf16x8*)(lds + a1 + mf * 1024);
    }
#pragma unroll
    for (int nf = 0; nf < 4; ++nf) bfr[nf] = *(const bf16x8*)(lds + bs + b0 + nf * 1024);
    asm volatile("s_waitcnt lgkmcnt(0)" ::: "memory");   // reads complete pre-barrier (WAR)
    __builtin_amdgcn_s_barrier();

    // ---- stage tile t+1: A in place, B into other slot
#pragma unroll
    for (int i = 0; i < 8; ++i) stage16(pA + (size_t)(i * 32) * KS + kn, lds + dA0 + i * 2048);
#pragma unroll
    for (int i = 0; i < 4; ++i) stage16(pB + (size_t)(i * 32) * KS + kn, lds + bn + dB0 + i * 2048);
    __builtin_amdgcn_sched_barrier(0);

    // ---- 32 MFMA ks0 (regs only)
    __builtin_amdgcn_s_setprio(1);
#pragma unroll
    for (int mf = 0; mf < 8; ++mf)
#pragma unroll
      for (int nf = 0; nf < 4; ++nf)
        acc[mf][nf] = __builtin_amdgcn_mfma_f32_16x16x32_bf16(af[mf][0], bfr[nf], acc[mf][nf], 0, 0, 0);
    __builtin_amdgcn_s_setprio(0);

    // ---- read B ks=1 (current slot: not a stage target) ; 32 MFMA ks1
#pragma unroll
    for (int nf = 0; nf < 4; ++nf) bfr[nf] = *(const bf16x8*)(lds + bs + b1 + nf * 1024);
    __builtin_amdgcn_s_setprio(1);
#pragma unroll
    for (int mf = 0; mf < 8; ++mf)
#pragma unroll
      for (int nf = 0; nf < 4; ++nf)
        acc[mf][nf] = __builtin_amdgcn_mfma_f32_16x16x32_bf16(af[mf][1], bfr[nf], acc[mf][nf], 0, 0, 0);
    __builtin_amdgcn_s_setprio(0);

    // ---- end-of-tile: tile t+1 resident, collectively visible
    asm volatile("s_waitcnt vmcnt(0)" ::: "memory");
    __builtin_amdgcn_s_barrier();
  }
}

// ---------------- GEMM A: h = (gelu(x@Wg) * (x@Wv)) * scale * cw ----------------
__global__ void __launch_bounds__(256, 2)
gemm_gv_kernel(const u16* __restrict__ xb, const u16* __restrict__ wgvT,
               const float* __restrict__ disp, const float* __restrict__ comb,
               const float* __restrict__ scale, u16* __restrict__ h) {
  __shared__ u16 lds[32768];   // 64 KB -> 2 blocks/CU

  // XCD swizzle: 4096 wgs, 512/expert -> expert e on XCD e
  const int bid = blockIdx.x;
  const int wg = (bid & 7) * 512 + (bid >> 3);
  const int e  = wg >> 9;
  const int rr = wg & 511;
  const int nt = rr >> 3;          // 0..63 (N' tiles of 128)
  const int mt = rr & 7;           // 0..7  (M tiles of 256)

  const int tid = threadIdx.x;
  const int lane = tid & 63;
  const int wave = tid >> 6;
  const int wm = wave >> 1, wn = wave & 1;
  const int l15 = lane & 15, lkq = lane >> 4;

  const u16* Bb = wgvT + (size_t)e * NPRIME * DDIM;
  const int Am0 = mt * 256;
  const int Bn0 = nt * 128;

  f32x4 acc[8][4] = {};
  gemm_loop<DDIM>(xb, Bb, Am0, Bn0, 0, DDIM / 64, lds, tid, acc);

  const float s_e = scale[e];
  const int hbase = nt * 64 + wn * 32;   // H-col base within expert
#pragma unroll
  for (int a = 0; a < 8; ++a) {
#pragma unroll
    for (int r = 0; r < 4; ++r) {
      const int t = Am0 + wm * 128 + a * 16 + lkq * 4 + r;
      const float dv = disp[t * NEXP + e];
      const float cv = comb[t * NEXP + e];
      const float s = (dv > 0.0f) ? cv * s_e : 0.0f;
#pragma unroll
      for (int jj = 0; jj < 2; ++jj) {
        const float g = acc[a][2 * jj][r];
        const float v = acc[a][2 * jj + 1][r];
        const float ge = 0.5f * g * (1.0f + erff(g * 0.70710678f));
        h[(size_t)t * KTOT + e * HDIM + hbase + jj * 16 + l15] = f2bf(ge * v * s);
      }
    }
  }
}

// ---------------- GEMM B: P[kz] = h[T][EH] @ woT2[D][EH]^T (split-K 8) ----------------
__global__ void __launch_bounds__(256, 2)
gemm_out_kernel(const u16* __restrict__ hb, const u16* __restrict__ woT2,
                float* __restrict__ P) {
  __shared__ u16 lds[32768];

  const int bid = blockIdx.x;          // 512 wgs
  const int wg = (bid & 7) * 64 + (bid >> 3);
  const int kz = wg >> 6;              // 0..7, one per XCD
  const int rr = wg & 63;
  const int nt = rr >> 3;              // 0..7 (D tiles of 128)
  const int mt = rr & 7;               // 0..7 (token tiles of 256)

  const int tid = threadIdx.x;
  const int lane = tid & 63;
  const int wave = tid >> 6;
  const int wm = wave >> 1, wn = wave & 1;
  const int l15 = lane & 15, lkq = lane >> 4;

  const int Am0 = mt * 256;
  const int Bn0 = nt * 128;
  const int kbase = kz * (KTOT / NSPLIT);   // 4096 per split

  f32x4 acc[8][4] = {};
  gemm_loop<KTOT>(hb, woT2, Am0, Bn0, kbase, (KTOT / NSPLIT) / 64, lds, tid, acc);

  float* Pp = P + (size_t)kz * (T_TOK * DDIM);
#pragma unroll
  for (int a = 0; a < 8; ++a) {
#pragma unroll
    for (int r = 0; r < 4; ++r) {
      const int t = Am0 + wm * 128 + a * 16 + lkq * 4 + r;
#pragma unroll
      for (int nf = 0; nf < 4; ++nf)
        Pp[(size_t)t * DDIM + Bn0 + wn * 64 + nf * 16 + l15] = acc[a][nf][r];
    }
  }
}

// ---------------- final: out = sum of NSPLIT partials ----------------
__global__ void reduce_out_kernel(const float* __restrict__ P, float* __restrict__ out) {
  int i = blockIdx.x * 256 + threadIdx.x;
  float4 a = ((const float4*)P)[i];
#pragma unroll
  for (int s = 1; s < NSPLIT; ++s) {
    float4 b = ((const float4*)P)[i + s * (T_TOK * DDIM / 4)];
    a.x += b.x; a.y += b.y; a.z += b.z; a.w += b.w;
  }
  ((float4*)out)[i] = a;
}

extern "C" void kernel_launch(void* const* d_in, const int* in_sizes, int n_in,
                              void* d_out, int out_size, void* d_ws, size_t ws_size,
                              hipStream_t stream) {
  const float* tokens = (const float*)d_in[0];
  const float* disp   = (const float*)d_in[1];
  const float* comb   = (const float*)d_in[2];
  const float* Wg     = (const float*)d_in[3];
  const float* Wv     = (const float*)d_in[4];
  const float* Wo     = (const float*)d_in[5];
  const float* scale  = (const float*)d_in[6];
  float* out = (float*)d_out;

  char* ws = (char*)d_ws;
  const size_t MB = 1024 * 1024;
  u16* xb    = (u16*)(ws);              // 4 MB   [T][D] bf16
  u16* wgvT  = (u16*)(ws + 4   * MB);   // 128 MB [E][8192][D] interleaved g/v
  u16* woT2  = (u16*)(ws + 132 * MB);   // 64 MB  [D][E*H]
  u16* hbuf  = (u16*)(ws + 196 * MB);   // 128 MB [T][E*H]
  float* P   = (float*)(ws + 324 * MB); // 64 MB  NSPLIT x [T][D] fp32

  cvt_x_kernel<<<1024, 256, 0, stream>>>(tokens, xb);
  transpose_all_kernel<<<24576, 256, 0, stream>>>(Wg, Wv, Wo, wgvT, woT2);
  gemm_gv_kernel<<<4096, 256, 0, stream>>>(xb, wgvT, disp, comb, scale, hbuf);
  gemm_out_kernel<<<512, 256, 0, stream>>>(hbuf, woT2, P);
  reduce_out_kernel<<<2048, 256, 0, stream>>>(P, out);
}

// Round 14
// 513.031 us; speedup vs baseline: 7.4135x; 1.0994x over previous
//
#include <hip/hip_runtime.h>
#include <math.h>

#define T_TOK 2048
#define DDIM 1024
#define HDIM 4096
#define NEXP 8
#define NPRIME 8192            // 2*HDIM interleaved g/v cols per expert
#define KTOT (NEXP * HDIM)     // 32768
#define NSPLIT 8

typedef unsigned short u16;
typedef __attribute__((ext_vector_type(4))) float f32x4;
typedef __attribute__((ext_vector_type(8))) __bf16 bf16x8;
typedef __attribute__((ext_vector_type(8))) unsigned short u16x8;
typedef __attribute__((ext_vector_type(4))) unsigned short u16x4;

__device__ __forceinline__ u16 f2bf(float f) {
  unsigned int u = __builtin_bit_cast(unsigned int, f);
  u += 0x7fffu + ((u >> 16) & 1u);   // round-to-nearest-even
  return (u16)(u >> 16);
}

// tanh-form gelu via hardware exp2/rcp (~10 instrs vs erff's ~30).
// |gelu_tanh - gelu_exact| <= ~4e-4 abs; propagated to output ~7e-7
// (<< 1.65e-4 threshold). Limits: g->+inf -> g ; g->-inf -> 0.
__device__ __forceinline__ float fast_gelu(float g) {
  float g2 = g * g;
  float y  = g * (0.7978845608f + 0.0356774081f * g2);  // sqrt(2/pi)*(g+0.044715 g^3)
  float e  = __builtin_amdgcn_exp2f(2.8853901817f * y); // 2^(2y*log2 e) = e^(2y)
  float t  = 1.0f - 2.0f * __builtin_amdgcn_rcpf(1.0f + e);
  return 0.5f * g * (1.0f + t);
}

__device__ __forceinline__ void stage16(const u16* g, u16* l) {
  __builtin_amdgcn_global_load_lds((__attribute__((address_space(1))) void*)g,
                                   (__attribute__((address_space(3))) void*)l,
                                   16, 0, 0);
}

// ---------------- prep: x fp32 -> bf16 ----------------
__global__ void cvt_x_kernel(const float* __restrict__ x, u16* __restrict__ xb) {
  int i = (blockIdx.x * 256 + threadIdx.x) * 8;
  float4 a = *(const float4*)(x + i);
  float4 b = *(const float4*)(x + i + 4);
  u16x8 o;
  o[0] = f2bf(a.x); o[1] = f2bf(a.y); o[2] = f2bf(a.z); o[3] = f2bf(a.w);
  o[4] = f2bf(b.x); o[5] = f2bf(b.y); o[6] = f2bf(b.z); o[7] = f2bf(b.w);
  *(u16x8*)(xb + i) = o;
}

// ---------------- prep: transpose+cvt all experts ----------------
__global__ void transpose_all_kernel(const float* __restrict__ Wg,
                                     const float* __restrict__ Wv,
                                     const float* __restrict__ Wo,
                                     u16* __restrict__ wgvT, u16* __restrict__ woT2) {
  __shared__ float lds[64][65];
  const int bid = blockIdx.x;           // 24576 = 8e * 3mat * 1024 tiles
  const int e = bid / 3072;
  const int r = bid % 3072;
  const int which = r >> 10;            // 0=Wg 1=Wv 2=Wo
  const int tt = r & 1023;
  const float* src; int R, C;
  if (which == 2) { src = Wo + (size_t)e * HDIM * DDIM; R = HDIM; C = DDIM; }
  else            { src = (which ? Wv : Wg) + (size_t)e * DDIM * HDIM; R = DDIM; C = HDIM; }
  const int nrt = R >> 6;
  const int r0 = (tt % nrt) << 6, c0 = (tt / nrt) << 6;
  const int tid = threadIdx.x;
#pragma unroll
  for (int i = 0; i < 4; ++i) {
    int f4 = tid + 256 * i;
    int row = f4 >> 4, c4 = (f4 & 15) << 2;
    float4 v = *(const float4*)(src + (size_t)(r0 + row) * C + c0 + c4);
    lds[row][c4] = v.x; lds[row][c4 + 1] = v.y; lds[row][c4 + 2] = v.z; lds[row][c4 + 3] = v.w;
  }
  __syncthreads();
#pragma unroll
  for (int i = 0; i < 4; ++i) {
    int f4 = tid + 256 * i;
    int cc = f4 >> 4, r4 = (f4 & 15) << 2;
    u16x4 o;
    o[0] = f2bf(lds[r4][cc]);     o[1] = f2bf(lds[r4 + 1][cc]);
    o[2] = f2bf(lds[r4 + 2][cc]); o[3] = f2bf(lds[r4 + 3][cc]);
    u16* dst;
    if (which == 2) {
      dst = woT2 + (size_t)(c0 + cc) * KTOT + e * HDIM + r0 + r4;
    } else {
      int h = c0 + cc;
      int rowp = ((h >> 4) << 5) + which * 16 + (h & 15);
      dst = wgvT + (size_t)e * NPRIME * DDIM + (size_t)rowp * DDIM + r0 + r4;
    }
    *(u16x4*)dst = o;
  }
}

// =================================================================
// gemm_loop4 (gv): BM=256, BN=128, BK=64, 4 waves, 256 thr, 64 KB LDS
// -> 2 blocks/CU (R13, best measured gv config).
// =================================================================
template<int KS>
__device__ __forceinline__ void gemm_loop4(const u16* Ab, const u16* Bb,
                                           int Am0, int Bn0, int kbase, int NT,
                                           u16* lds, int tid, f32x4 (&acc)[8][4]) {
  const int lane = tid & 63;
  const int wave = tid >> 6;            // 0..3
  const int wm = wave >> 1, wn = wave & 1;
  const int l15 = lane & 15, lkq = lane >> 4;

  const int sl = tid & 7, r0 = tid >> 3;          // r0 0..31
  const int slx = (sl ^ (r0 & 7)) << 3;
  const u16* pA = Ab + (size_t)(Am0 + r0) * KS + kbase + slx;
  const u16* pB = Bb + (size_t)(Bn0 + r0) * KS + kbase + slx;
  const int dA0 = r0 * 64 + sl * 8;
  const int dB0 = r0 * 64 + sl * 8;

  const int swz0 = (lkq ^ (l15 & 7)) << 3;
  const int swz1 = ((4 | lkq) ^ (l15 & 7)) << 3;
  const int arow = (wm * 128 + l15) * 64;
  const int brow = (wn * 64 + l15) * 64;
  const int a0 = arow + swz0, a1 = arow + swz1;
  const int b0 = brow + swz0, b1 = brow + swz1;

#pragma unroll
  for (int i = 0; i < 8; ++i) stage16(pA + (size_t)(i * 32) * KS, lds + dA0 + i * 2048);
#pragma unroll
  for (int i = 0; i < 4; ++i) stage16(pB + (size_t)(i * 32) * KS, lds + 16384 + dB0 + i * 2048);
  asm volatile("s_waitcnt vmcnt(0)" ::: "memory");
  __builtin_amdgcn_s_barrier();

#pragma unroll 1
  for (int t = 0; t < NT; ++t) {
    const int bs = 16384 + ((t & 1) << 13);
    const int bn = 16384 + (((t + 1) & 1) << 13);
    const int tp1 = (t + 1 < NT) ? t + 1 : NT - 1;
    const size_t kn = (size_t)(tp1 << 6);
    bf16x8 af[8][2], bfr[4];

#pragma unroll
    for (int mf = 0; mf < 8; ++mf) {
      af[mf][0] = *(const bf16x8*)(lds + a0 + mf * 1024);
      af[mf][1] = *(const bf16x8*)(lds + a1 + mf * 1024);
    }
#pragma unroll
    for (int nf = 0; nf < 4; ++nf) bfr[nf] = *(const bf16x8*)(lds + bs + b0 + nf * 1024);
    asm volatile("s_waitcnt lgkmcnt(0)" ::: "memory");
    __builtin_amdgcn_s_barrier();

#pragma unroll
    for (int i = 0; i < 8; ++i) stage16(pA + (size_t)(i * 32) * KS + kn, lds + dA0 + i * 2048);
#pragma unroll
    for (int i = 0; i < 4; ++i) stage16(pB + (size_t)(i * 32) * KS + kn, lds + bn + dB0 + i * 2048);
    __builtin_amdgcn_sched_barrier(0);

    __builtin_amdgcn_s_setprio(1);
#pragma unroll
    for (int mf = 0; mf < 8; ++mf)
#pragma unroll
      for (int nf = 0; nf < 4; ++nf)
        acc[mf][nf] = __builtin_amdgcn_mfma_f32_16x16x32_bf16(af[mf][0], bfr[nf], acc[mf][nf], 0, 0, 0);
    __builtin_amdgcn_s_setprio(0);

#pragma unroll
    for (int nf = 0; nf < 4; ++nf) bfr[nf] = *(const bf16x8*)(lds + bs + b1 + nf * 1024);
    __builtin_amdgcn_s_setprio(1);
#pragma unroll
    for (int mf = 0; mf < 8; ++mf)
#pragma unroll
      for (int nf = 0; nf < 4; ++nf)
        acc[mf][nf] = __builtin_amdgcn_mfma_f32_16x16x32_bf16(af[mf][1], bfr[nf], acc[mf][nf], 0, 0, 0);
    __builtin_amdgcn_s_setprio(0);

    asm volatile("s_waitcnt vmcnt(0)" ::: "memory");
    __builtin_amdgcn_s_barrier();
  }
}

// ---------------- GEMM A: h = (gelu(x@Wg) * (x@Wv)) * scale * cw ----------------
__global__ void __launch_bounds__(256, 2)
gemm_gv_kernel(const u16* __restrict__ xb, const u16* __restrict__ wgvT,
               const float* __restrict__ disp, const float* __restrict__ comb,
               const float* __restrict__ scale, u16* __restrict__ h) {
  __shared__ u16 lds[32768];   // 64 KB -> 2 blocks/CU

  const int bid = blockIdx.x;
  const int wg = (bid & 7) * 512 + (bid >> 3);
  const int e  = wg >> 9;
  const int rr = wg & 511;
  const int nt = rr >> 3;          // 0..63 (N' tiles of 128)
  const int mt = rr & 7;           // 0..7  (M tiles of 256)

  const int tid = threadIdx.x;
  const int lane = tid & 63;
  const int wave = tid >> 6;
  const int wm = wave >> 1, wn = wave & 1;
  const int l15 = lane & 15, lkq = lane >> 4;

  const u16* Bb = wgvT + (size_t)e * NPRIME * DDIM;
  const int Am0 = mt * 256;
  const int Bn0 = nt * 128;

  f32x4 acc[8][4] = {};
  gemm_loop4<DDIM>(xb, Bb, Am0, Bn0, 0, DDIM / 64, lds, tid, acc);

  const float s_e = scale[e];
  const int hbase = nt * 64 + wn * 32;   // H-col base within expert
#pragma unroll
  for (int a = 0; a < 8; ++a) {
#pragma unroll
    for (int r = 0; r < 4; ++r) {
      const int t = Am0 + wm * 128 + a * 16 + lkq * 4 + r;
      const float dv = disp[t * NEXP + e];
      const float cv = comb[t * NEXP + e];
      const float s = (dv > 0.0f) ? cv * s_e : 0.0f;
#pragma unroll
      for (int jj = 0; jj < 2; ++jj) {
        const float g = acc[a][2 * jj][r];
        const float v = acc[a][2 * jj + 1][r];
        h[(size_t)t * KTOT + e * HDIM + hbase + jj * 16 + l15] = f2bf(fast_gelu(g) * v * s);
      }
    }
  }
}

// =================================================================
// gemm_loop8 (out): BM=256, BN=256, BK=64, 8 waves, 512 thr, 128 KB LDS,
// quarter-replacement staging, vmcnt(10) ledger (R9, best measured out).
// =================================================================
template<int KS>
__device__ __forceinline__ void gemm_loop8(const u16* Ab, const u16* Bb,
                                           int Am0, int Bn0, int kbase, int NT,
                                           u16* lds, int tid, f32x4 (&acc)[8][4]) {
  const int lane = tid & 63;
  const int wave = tid >> 6;
  const int wm = wave >> 2, wn = wave & 3;
  const int l15 = lane & 15, lkq = lane >> 4;

  const int sl = tid & 7, rw = tid >> 3;
  const int slx = (sl ^ (rw & 7)) << 3;
  const int rb = (rw & 31) + ((rw >> 5) << 6);
  const u16* pA = Ab + (size_t)(Am0 + rw) * KS + kbase + slx;
  const u16* pB = Bb + (size_t)(Bn0 + rb) * KS + kbase + slx;
  const int dA = rw * 64 + sl * 8;
  const int dB = 16384 + rb * 64 + sl * 8;

  auto slot = [&](int t) -> u16* { return lds + (t & 1) * 32768; };
  auto SA0 = [&](int t) { u16* sp = slot(t); const int k = t << 6;
    stage16(pA + k, sp + dA);
    stage16(pA + (size_t)128 * KS + k, sp + dA + 8192); };
  auto SA1 = [&](int t) { u16* sp = slot(t); const int k = t << 6;
    stage16(pA + (size_t)64 * KS + k, sp + dA + 4096);
    stage16(pA + (size_t)192 * KS + k, sp + dA + 12288); };
  auto SB0 = [&](int t) { u16* sp = slot(t); const int k = t << 6;
    stage16(pB + k, sp + dB);
    stage16(pB + (size_t)128 * KS + k, sp + dB + 8192); };
  auto SB1 = [&](int t) { u16* sp = slot(t); const int k = t << 6;
    stage16(pB + (size_t)32 * KS + k, sp + dB + 2048);
    stage16(pB + (size_t)160 * KS + k, sp + dB + 10240); };

  const int swz0 = (lkq ^ (l15 & 7)) << 3;
  const int swz1 = ((4 | lkq) ^ (l15 & 7)) << 3;
  const int arow = (wm * 128 + l15) * 64;
  const int brow = 16384 + (wn * 64 + l15) * 64;
  const int a0 = arow + swz0, a1 = arow + swz1;
  const int b0 = brow + swz0, b1 = brow + swz1;

  SA0(0); SB0(0); SB1(0); SA1(0);
  SA0(1); SB0(1); SB1(1);
  asm volatile("s_waitcnt vmcnt(10)" ::: "memory");
  __builtin_amdgcn_s_barrier();

#pragma unroll 1
  for (int t = 0; t < NT; ++t) {
    const u16* s = slot(t);
    const int tp1 = (t + 1 < NT) ? t + 1 : NT - 1;
    const int tp2 = (t + 2 < NT) ? t + 2 : NT - 1;
    bf16x8 af[4][2], bfr[4][2];

#pragma unroll
    for (int mf = 0; mf < 4; ++mf) {
      af[mf][0] = *(const bf16x8*)(s + a0 + mf * 1024);
      af[mf][1] = *(const bf16x8*)(s + a1 + mf * 1024);
    }
#pragma unroll
    for (int nf = 0; nf < 2; ++nf) {
      bfr[nf][0] = *(const bf16x8*)(s + b0 + nf * 1024);
      bfr[nf][1] = *(const bf16x8*)(s + b1 + nf * 1024);
    }
    SA1(tp1);
    asm volatile("s_waitcnt vmcnt(10)" ::: "memory");
    __builtin_amdgcn_s_barrier();
    asm volatile("s_waitcnt lgkmcnt(0)" ::: "memory");
    __builtin_amdgcn_sched_barrier(0);
    __builtin_amdgcn_s_setprio(1);
#pragma unroll
    for (int ks = 0; ks < 2; ++ks)
#pragma unroll
      for (int mf = 0; mf < 4; ++mf)
#pragma unroll
        for (int nf = 0; nf < 2; ++nf)
          acc[mf][nf] = __builtin_amdgcn_mfma_f32_16x16x32_bf16(af[mf][ks], bfr[nf][ks], acc[mf][nf], 0, 0, 0);
    __builtin_amdgcn_s_setprio(0);
    __builtin_amdgcn_s_barrier();

#pragma unroll
    for (int nf = 2; nf < 4; ++nf) {
      bfr[nf][0] = *(const bf16x8*)(s + b0 + nf * 1024);
      bfr[nf][1] = *(const bf16x8*)(s + b1 + nf * 1024);
    }
    SA0(tp2);
    asm volatile("s_waitcnt vmcnt(10)" ::: "memory");
    __builtin_amdgcn_s_barrier();
    asm volatile("s_waitcnt lgkmcnt(0)" ::: "memory");
    __builtin_amdgcn_sched_barrier(0);
    __builtin_amdgcn_s_setprio(1);
#pragma unroll
    for (int ks = 0; ks < 2; ++ks)
#pragma unroll
      for (int mf = 0; mf < 4; ++mf)
#pragma unroll
        for (int nf = 2; nf < 4; ++nf)
          acc[mf][nf] = __builtin_amdgcn_mfma_f32_16x16x32_bf16(af[mf][ks], bfr[nf][ks], acc[mf][nf], 0, 0, 0);
    __builtin_amdgcn_s_setprio(0);
    __builtin_amdgcn_s_barrier();

#pragma unroll
    for (int mf = 0; mf < 4; ++mf) {
      af[mf][0] = *(const bf16x8*)(s + a0 + 4096 + mf * 1024);
      af[mf][1] = *(const bf16x8*)(s + a1 + 4096 + mf * 1024);
    }
    SB0(tp2);
    __builtin_amdgcn_s_barrier();
    asm volatile("s_waitcnt lgkmcnt(0)" ::: "memory");
    __builtin_amdgcn_sched_barrier(0);
    __builtin_amdgcn_s_setprio(1);
#pragma unroll
    for (int ks = 0; ks < 2; ++ks)
#pragma unroll
      for (int mf = 0; mf < 4; ++mf)
#pragma unroll
        for (int nf = 0; nf < 2; ++nf)
          acc[4 + mf][nf] = __builtin_amdgcn_mfma_f32_16x16x32_bf16(af[mf][ks], bfr[nf][ks], acc[4 + mf][nf], 0, 0, 0);
    __builtin_amdgcn_s_setprio(0);
    __builtin_amdgcn_s_barrier();

    SB1(tp2);
    asm volatile("s_waitcnt vmcnt(10)" ::: "memory");
    __builtin_amdgcn_s_barrier();
    __builtin_amdgcn_s_setprio(1);
#pragma unroll
    for (int ks = 0; ks < 2; ++ks)
#pragma unroll
      for (int mf = 0; mf < 4; ++mf)
#pragma unroll
        for (int nf = 2; nf < 4; ++nf)
          acc[4 + mf][nf] = __builtin_amdgcn_mfma_f32_16x16x32_bf16(af[mf][ks], bfr[nf][ks], acc[4 + mf][nf], 0, 0, 0);
    __builtin_amdgcn_s_setprio(0);
    __builtin_amdgcn_s_barrier();
  }
}

// ---------------- GEMM B: P[kz] = h[T][EH] @ woT2[D][EH]^T (split-K 8) ----------------
__global__ void __launch_bounds__(512, 2)
gemm_out_kernel(const u16* __restrict__ hb, const u16* __restrict__ woT2,
                float* __restrict__ P) {
  __shared__ u16 lds[65536];

  const int bid = blockIdx.x;          // 256 wgs
  const int wg = (bid & 7) * 32 + (bid >> 3);
  const int kz = wg >> 5;              // 0..7, one per XCD
  const int rr = wg & 31;
  const int nt = rr >> 3;              // 0..3 (D tiles of 256)
  const int mt = rr & 7;               // 0..7 (token tiles of 256)

  const int tid = threadIdx.x;
  const int lane = tid & 63;
  const int wave = tid >> 6;
  const int wm = wave >> 2, wn = wave & 3;
  const int l15 = lane & 15, lkq = lane >> 4;

  const int Am0 = mt * 256;
  const int Bn0 = nt * 256;
  const int kbase = kz * (KTOT / NSPLIT);   // 4096 per split

  f32x4 acc[8][4] = {};
  gemm_loop8<KTOT>(hb, woT2, Am0, Bn0, kbase, (KTOT / NSPLIT) / 64, lds, tid, acc);

  float* Pp = P + (size_t)kz * (T_TOK * DDIM);
#pragma unroll
  for (int a = 0; a < 8; ++a) {
#pragma unroll
    for (int r = 0; r < 4; ++r) {
      const int t = Am0 + wm * 128 + a * 16 + lkq * 4 + r;
#pragma unroll
      for (int nf = 0; nf < 4; ++nf)
        Pp[(size_t)t * DDIM + Bn0 + wn * 64 + nf * 16 + l15] = acc[a][nf][r];
    }
  }
}

// ---------------- final: out = sum of NSPLIT partials ----------------
__global__ void reduce_out_kernel(const float* __restrict__ P, float* __restrict__ out) {
  int i = blockIdx.x * 256 + threadIdx.x;
  float4 a = ((const float4*)P)[i];
#pragma unroll
  for (int s = 1; s < NSPLIT; ++s) {
    float4 b = ((const float4*)P)[i + s * (T_TOK * DDIM / 4)];
    a.x += b.x; a.y += b.y; a.z += b.z; a.w += b.w;
  }
  ((float4*)out)[i] = a;
}

extern "C" void kernel_launch(void* const* d_in, const int* in_sizes, int n_in,
                              void* d_out, int out_size, void* d_ws, size_t ws_size,
                              hipStream_t stream) {
  const float* tokens = (const float*)d_in[0];
  const float* disp   = (const float*)d_in[1];
  const float* comb   = (const float*)d_in[2];
  const float* Wg     = (const float*)d_in[3];
  const float* Wv     = (const float*)d_in[4];
  const float* Wo     = (const float*)d_in[5];
  const float* scale  = (const float*)d_in[6];
  float* out = (float*)d_out;

  char* ws = (char*)d_ws;
  const size_t MB = 1024 * 1024;
  u16* xb    = (u16*)(ws);              // 4 MB   [T][D] bf16
  u16* wgvT  = (u16*)(ws + 4   * MB);   // 128 MB [E][8192][D] interleaved g/v
  u16* woT2  = (u16*)(ws + 132 * MB);   // 64 MB  [D][E*H]
  u16* hbuf  = (u16*)(ws + 196 * MB);   // 128 MB [T][E*H]
  float* P   = (float*)(ws + 324 * MB); // 64 MB  NSPLIT x [T][D] fp32

  cvt_x_kernel<<<1024, 256, 0, stream>>>(tokens, xb);
  transpose_all_kernel<<<24576, 256, 0, stream>>>(Wg, Wv, Wo, wgvT, woT2);
  gemm_gv_kernel<<<4096, 256, 0, stream>>>(xb, wgvT, disp, comb, scale, hbuf);
  gemm_out_kernel<<<256, 512, 0, stream>>>(hbuf, woT2, P);
  reduce_out_kernel<<<2048, 256, 0, stream>>>(P, out);
}

// Round 15
// 507.654 us; speedup vs baseline: 7.4920x; 1.0106x over previous
//
#include <hip/hip_runtime.h>
#include <math.h>

#define T_TOK 2048
#define DDIM 1024
#define HDIM 4096
#define NEXP 8
#define NPRIME 8192            // 2*HDIM interleaved g/v cols per expert
#define KTOT (NEXP * HDIM)     // 32768
#define NSPLIT 8

typedef unsigned short u16;
typedef __attribute__((ext_vector_type(4))) float f32x4;
typedef __attribute__((ext_vector_type(8))) __bf16 bf16x8;
typedef __attribute__((ext_vector_type(8))) unsigned short u16x8;
typedef __attribute__((ext_vector_type(4))) unsigned short u16x4;

__device__ __forceinline__ u16 f2bf(float f) {
  unsigned int u = __builtin_bit_cast(unsigned int, f);
  u += 0x7fffu + ((u >> 16) & 1u);   // round-to-nearest-even
  return (u16)(u >> 16);
}

// tanh-form gelu via hardware exp2/rcp (~10 instrs vs erff's ~30).
// |gelu_tanh - gelu_exact| <= ~4e-4 abs; propagated to output ~1e-6
// (<< 1.65e-4 threshold). Verified R14: absmax 3.8e-5.
__device__ __forceinline__ float fast_gelu(float g) {
  float g2 = g * g;
  float y  = g * (0.7978845608f + 0.0356774081f * g2);  // sqrt(2/pi)*(g+0.044715 g^3)
  float e  = __builtin_amdgcn_exp2f(2.8853901817f * y); // e^(2y)
  float t  = 1.0f - 2.0f * __builtin_amdgcn_rcpf(1.0f + e);
  return 0.5f * g * (1.0f + t);
}

__device__ __forceinline__ void stage16(const u16* g, u16* l) {
  __builtin_amdgcn_global_load_lds((__attribute__((address_space(1))) void*)g,
                                   (__attribute__((address_space(3))) void*)l,
                                   16, 0, 0);
}

// ---------------- prep (merged): x cvt + all-expert weight transpose ----------------
// blocks [0,1024):    xb[i] = bf16(tokens[i])          (2M elems, x8/thread)
// blocks [1024,25600): 64x64 transpose+cvt tiles of Wg/Wv/Wo
__global__ void prep_all_kernel(const float* __restrict__ x, u16* __restrict__ xb,
                                const float* __restrict__ Wg,
                                const float* __restrict__ Wv,
                                const float* __restrict__ Wo,
                                u16* __restrict__ wgvT, u16* __restrict__ woT2) {
  const int tid = threadIdx.x;
  int bid = blockIdx.x;
  if (bid < 1024) {
    int i = (bid * 256 + tid) * 8;
    float4 a = *(const float4*)(x + i);
    float4 b = *(const float4*)(x + i + 4);
    u16x8 o;
    o[0] = f2bf(a.x); o[1] = f2bf(a.y); o[2] = f2bf(a.z); o[3] = f2bf(a.w);
    o[4] = f2bf(b.x); o[5] = f2bf(b.y); o[6] = f2bf(b.z); o[7] = f2bf(b.w);
    *(u16x8*)(xb + i) = o;
    return;
  }
  bid -= 1024;                          // 24576 = 8e * 3mat * 1024 tiles
  __shared__ float lds[64][65];
  const int e = bid / 3072;
  const int r = bid % 3072;
  const int which = r >> 10;            // 0=Wg 1=Wv 2=Wo
  const int tt = r & 1023;
  const float* src; int R, C;
  if (which == 2) { src = Wo + (size_t)e * HDIM * DDIM; R = HDIM; C = DDIM; }
  else            { src = (which ? Wv : Wg) + (size_t)e * DDIM * HDIM; R = DDIM; C = HDIM; }
  const int nrt = R >> 6;
  const int r0 = (tt % nrt) << 6, c0 = (tt / nrt) << 6;
#pragma unroll
  for (int i = 0; i < 4; ++i) {
    int f4 = tid + 256 * i;
    int row = f4 >> 4, c4 = (f4 & 15) << 2;
    float4 v = *(const float4*)(src + (size_t)(r0 + row) * C + c0 + c4);
    lds[row][c4] = v.x; lds[row][c4 + 1] = v.y; lds[row][c4 + 2] = v.z; lds[row][c4 + 3] = v.w;
  }
  __syncthreads();
#pragma unroll
  for (int i = 0; i < 4; ++i) {
    int f4 = tid + 256 * i;
    int cc = f4 >> 4, r4 = (f4 & 15) << 2;
    u16x4 o;
    o[0] = f2bf(lds[r4][cc]);     o[1] = f2bf(lds[r4 + 1][cc]);
    o[2] = f2bf(lds[r4 + 2][cc]); o[3] = f2bf(lds[r4 + 3][cc]);
    u16* dst;
    if (which == 2) {
      dst = woT2 + (size_t)(c0 + cc) * KTOT + e * HDIM + r0 + r4;
    } else {
      int h = c0 + cc;
      int rowp = ((h >> 4) << 5) + which * 16 + (h & 15);
      dst = wgvT + (size_t)e * NPRIME * DDIM + (size_t)rowp * DDIM + r0 + r4;
    }
    *(u16x4*)dst = o;
  }
}

// =================================================================
// gemm_loop4 (gv): BM=256, BN=128, BK=64, 4 waves, 256 thr, 64 KB LDS
// -> 2 blocks/CU (best measured gv config, R13/R14).
// =================================================================
template<int KS>
__device__ __forceinline__ void gemm_loop4(const u16* Ab, const u16* Bb,
                                           int Am0, int Bn0, int kbase, int NT,
                                           u16* lds, int tid, f32x4 (&acc)[8][4]) {
  const int lane = tid & 63;
  const int wave = tid >> 6;            // 0..3
  const int wm = wave >> 1, wn = wave & 1;
  const int l15 = lane & 15, lkq = lane >> 4;

  const int sl = tid & 7, r0 = tid >> 3;          // r0 0..31
  const int slx = (sl ^ (r0 & 7)) << 3;
  const u16* pA = Ab + (size_t)(Am0 + r0) * KS + kbase + slx;
  const u16* pB = Bb + (size_t)(Bn0 + r0) * KS + kbase + slx;
  const int dA0 = r0 * 64 + sl * 8;
  const int dB0 = r0 * 64 + sl * 8;

  const int swz0 = (lkq ^ (l15 & 7)) << 3;
  const int swz1 = ((4 | lkq) ^ (l15 & 7)) << 3;
  const int arow = (wm * 128 + l15) * 64;
  const int brow = (wn * 64 + l15) * 64;
  const int a0 = arow + swz0, a1 = arow + swz1;
  const int b0 = brow + swz0, b1 = brow + swz1;

#pragma unroll
  for (int i = 0; i < 8; ++i) stage16(pA + (size_t)(i * 32) * KS, lds + dA0 + i * 2048);
#pragma unroll
  for (int i = 0; i < 4; ++i) stage16(pB + (size_t)(i * 32) * KS, lds + 16384 + dB0 + i * 2048);
  asm volatile("s_waitcnt vmcnt(0)" ::: "memory");
  __builtin_amdgcn_s_barrier();

#pragma unroll 1
  for (int t = 0; t < NT; ++t) {
    const int bs = 16384 + ((t & 1) << 13);
    const int bn = 16384 + (((t + 1) & 1) << 13);
    const int tp1 = (t + 1 < NT) ? t + 1 : NT - 1;
    const size_t kn = (size_t)(tp1 << 6);
    bf16x8 af[8][2], bfr[4];

#pragma unroll
    for (int mf = 0; mf < 8; ++mf) {
      af[mf][0] = *(const bf16x8*)(lds + a0 + mf * 1024);
      af[mf][1] = *(const bf16x8*)(lds + a1 + mf * 1024);
    }
#pragma unroll
    for (int nf = 0; nf < 4; ++nf) bfr[nf] = *(const bf16x8*)(lds + bs + b0 + nf * 1024);
    asm volatile("s_waitcnt lgkmcnt(0)" ::: "memory");
    __builtin_amdgcn_s_barrier();

#pragma unroll
    for (int i = 0; i < 8; ++i) stage16(pA + (size_t)(i * 32) * KS + kn, lds + dA0 + i * 2048);
#pragma unroll
    for (int i = 0; i < 4; ++i) stage16(pB + (size_t)(i * 32) * KS + kn, lds + bn + dB0 + i * 2048);
    __builtin_amdgcn_sched_barrier(0);

    __builtin_amdgcn_s_setprio(1);
#pragma unroll
    for (int mf = 0; mf < 8; ++mf)
#pragma unroll
      for (int nf = 0; nf < 4; ++nf)
        acc[mf][nf] = __builtin_amdgcn_mfma_f32_16x16x32_bf16(af[mf][0], bfr[nf], acc[mf][nf], 0, 0, 0);
    __builtin_amdgcn_s_setprio(0);

#pragma unroll
    for (int nf = 0; nf < 4; ++nf) bfr[nf] = *(const bf16x8*)(lds + bs + b1 + nf * 1024);
    __builtin_amdgcn_s_setprio(1);
#pragma unroll
    for (int mf = 0; mf < 8; ++mf)
#pragma unroll
      for (int nf = 0; nf < 4; ++nf)
        acc[mf][nf] = __builtin_amdgcn_mfma_f32_16x16x32_bf16(af[mf][1], bfr[nf], acc[mf][nf], 0, 0, 0);
    __builtin_amdgcn_s_setprio(0);

    asm volatile("s_waitcnt vmcnt(0)" ::: "memory");
    __builtin_amdgcn_s_barrier();
  }
}

// ---------------- GEMM A: h = (gelu(x@Wg) * (x@Wv)) * scale * cw ----------------
__global__ void __launch_bounds__(256, 2)
gemm_gv_kernel(const u16* __restrict__ xb, const u16* __restrict__ wgvT,
               const float* __restrict__ disp, const float* __restrict__ comb,
               const float* __restrict__ scale, u16* __restrict__ h) {
  __shared__ u16 lds[32768];   // 64 KB -> 2 blocks/CU

  const int bid = blockIdx.x;
  const int wg = (bid & 7) * 512 + (bid >> 3);
  const int e  = wg >> 9;
  const int rr = wg & 511;
  const int nt = rr >> 3;          // 0..63 (N' tiles of 128)
  const int mt = rr & 7;           // 0..7  (M tiles of 256)

  const int tid = threadIdx.x;
  const int lane = tid & 63;
  const int wave = tid >> 6;
  const int wm = wave >> 1, wn = wave & 1;
  const int l15 = lane & 15, lkq = lane >> 4;

  const u16* Bb = wgvT + (size_t)e * NPRIME * DDIM;
  const int Am0 = mt * 256;
  const int Bn0 = nt * 128;

  f32x4 acc[8][4] = {};
  gemm_loop4<DDIM>(xb, Bb, Am0, Bn0, 0, DDIM / 64, lds, tid, acc);

  const float s_e = scale[e];
  const int hbase = nt * 64 + wn * 32;   // H-col base within expert
#pragma unroll
  for (int a = 0; a < 8; ++a) {
#pragma unroll
    for (int r = 0; r < 4; ++r) {
      const int t = Am0 + wm * 128 + a * 16 + lkq * 4 + r;
      const float dv = disp[t * NEXP + e];
      const float cv = comb[t * NEXP + e];
      const float s = (dv > 0.0f) ? cv * s_e : 0.0f;
#pragma unroll
      for (int jj = 0; jj < 2; ++jj) {
        const float g = acc[a][2 * jj][r];
        const float v = acc[a][2 * jj + 1][r];
        h[(size_t)t * KTOT + e * HDIM + hbase + jj * 16 + l15] = f2bf(fast_gelu(g) * v * s);
      }
    }
  }
}

// =================================================================
// gemm_loop8 (out): BM=256, BN=256, BK=64, 8 waves, 512 thr, 128 KB LDS,
// quarter-replacement staging, vmcnt(10) ledger (best measured out, R9).
// =================================================================
template<int KS>
__device__ __forceinline__ void gemm_loop8(const u16* Ab, const u16* Bb,
                                           int Am0, int Bn0, int kbase, int NT,
                                           u16* lds, int tid, f32x4 (&acc)[8][4]) {
  const int lane = tid & 63;
  const int wave = tid >> 6;
  const int wm = wave >> 2, wn = wave & 3;
  const int l15 = lane & 15, lkq = lane >> 4;

  const int sl = tid & 7, rw = tid >> 3;
  const int slx = (sl ^ (rw & 7)) << 3;
  const int rb = (rw & 31) + ((rw >> 5) << 6);
  const u16* pA = Ab + (size_t)(Am0 + rw) * KS + kbase + slx;
  const u16* pB = Bb + (size_t)(Bn0 + rb) * KS + kbase + slx;
  const int dA = rw * 64 + sl * 8;
  const int dB = 16384 + rb * 64 + sl * 8;

  auto slot = [&](int t) -> u16* { return lds + (t & 1) * 32768; };
  auto SA0 = [&](int t) { u16* sp = slot(t); const int k = t << 6;
    stage16(pA + k, sp + dA);
    stage16(pA + (size_t)128 * KS + k, sp + dA + 8192); };
  auto SA1 = [&](int t) { u16* sp = slot(t); const int k = t << 6;
    stage16(pA + (size_t)64 * KS + k, sp + dA + 4096);
    stage16(pA + (size_t)192 * KS + k, sp + dA + 12288); };
  auto SB0 = [&](int t) { u16* sp = slot(t); const int k = t << 6;
    stage16(pB + k, sp + dB);
    stage16(pB + (size_t)128 * KS + k, sp + dB + 8192); };
  auto SB1 = [&](int t) { u16* sp = slot(t); const int k = t << 6;
    stage16(pB + (size_t)32 * KS + k, sp + dB + 2048);
    stage16(pB + (size_t)160 * KS + k, sp + dB + 10240); };

  const int swz0 = (lkq ^ (l15 & 7)) << 3;
  const int swz1 = ((4 | lkq) ^ (l15 & 7)) << 3;
  const int arow = (wm * 128 + l15) * 64;
  const int brow = 16384 + (wn * 64 + l15) * 64;
  const int a0 = arow + swz0, a1 = arow + swz1;
  const int b0 = brow + swz0, b1 = brow + swz1;

  SA0(0); SB0(0); SB1(0); SA1(0);
  SA0(1); SB0(1); SB1(1);
  asm volatile("s_waitcnt vmcnt(10)" ::: "memory");
  __builtin_amdgcn_s_barrier();

#pragma unroll 1
  for (int t = 0; t < NT; ++t) {
    const u16* s = slot(t);
    const int tp1 = (t + 1 < NT) ? t + 1 : NT - 1;
    const int tp2 = (t + 2 < NT) ? t + 2 : NT - 1;
    bf16x8 af[4][2], bfr[4][2];

#pragma unroll
    for (int mf = 0; mf < 4; ++mf) {
      af[mf][0] = *(const bf16x8*)(s + a0 + mf * 1024);
      af[mf][1] = *(const bf16x8*)(s + a1 + mf * 1024);
    }
#pragma unroll
    for (int nf = 0; nf < 2; ++nf) {
      bfr[nf][0] = *(const bf16x8*)(s + b0 + nf * 1024);
      bfr[nf][1] = *(const bf16x8*)(s + b1 + nf * 1024);
    }
    SA1(tp1);
    asm volatile("s_waitcnt vmcnt(10)" ::: "memory");
    __builtin_amdgcn_s_barrier();
    asm volatile("s_waitcnt lgkmcnt(0)" ::: "memory");
    __builtin_amdgcn_sched_barrier(0);
    __builtin_amdgcn_s_setprio(1);
#pragma unroll
    for (int ks = 0; ks < 2; ++ks)
#pragma unroll
      for (int mf = 0; mf < 4; ++mf)
#pragma unroll
        for (int nf = 0; nf < 2; ++nf)
          acc[mf][nf] = __builtin_amdgcn_mfma_f32_16x16x32_bf16(af[mf][ks], bfr[nf][ks], acc[mf][nf], 0, 0, 0);
    __builtin_amdgcn_s_setprio(0);
    __builtin_amdgcn_s_barrier();

#pragma unroll
    for (int nf = 2; nf < 4; ++nf) {
      bfr[nf][0] = *(const bf16x8*)(s + b0 + nf * 1024);
      bfr[nf][1] = *(const bf16x8*)(s + b1 + nf * 1024);
    }
    SA0(tp2);
    asm volatile("s_waitcnt vmcnt(10)" ::: "memory");
    __builtin_amdgcn_s_barrier();
    asm volatile("s_waitcnt lgkmcnt(0)" ::: "memory");
    __builtin_amdgcn_sched_barrier(0);
    __builtin_amdgcn_s_setprio(1);
#pragma unroll
    for (int ks = 0; ks < 2; ++ks)
#pragma unroll
      for (int mf = 0; mf < 4; ++mf)
#pragma unroll
        for (int nf = 2; nf < 4; ++nf)
          acc[mf][nf] = __builtin_amdgcn_mfma_f32_16x16x32_bf16(af[mf][ks], bfr[nf][ks], acc[mf][nf], 0, 0, 0);
    __builtin_amdgcn_s_setprio(0);
    __builtin_amdgcn_s_barrier();

#pragma unroll
    for (int mf = 0; mf < 4; ++mf) {
      af[mf][0] = *(const bf16x8*)(s + a0 + 4096 + mf * 1024);
      af[mf][1] = *(const bf16x8*)(s + a1 + 4096 + mf * 1024);
    }
    SB0(tp2);
    __builtin_amdgcn_s_barrier();
    asm volatile("s_waitcnt lgkmcnt(0)" ::: "memory");
    __builtin_amdgcn_sched_barrier(0);
    __builtin_amdgcn_s_setprio(1);
#pragma unroll
    for (int ks = 0; ks < 2; ++ks)
#pragma unroll
      for (int mf = 0; mf < 4; ++mf)
#pragma unroll
        for (int nf = 0; nf < 2; ++nf)
          acc[4 + mf][nf] = __builtin_amdgcn_mfma_f32_16x16x32_bf16(af[mf][ks], bfr[nf][ks], acc[4 + mf][nf], 0, 0, 0);
    __builtin_amdgcn_s_setprio(0);
    __builtin_amdgcn_s_barrier();

    SB1(tp2);
    asm volatile("s_waitcnt vmcnt(10)" ::: "memory");
    __builtin_amdgcn_s_barrier();
    __builtin_amdgcn_s_setprio(1);
#pragma unroll
    for (int ks = 0; ks < 2; ++ks)
#pragma unroll
      for (int mf = 0; mf < 4; ++mf)
#pragma unroll
        for (int nf = 2; nf < 4; ++nf)
          acc[4 + mf][nf] = __builtin_amdgcn_mfma_f32_16x16x32_bf16(af[mf][ks], bfr[nf][ks], acc[4 + mf][nf], 0, 0, 0);
    __builtin_amdgcn_s_setprio(0);
    __builtin_amdgcn_s_barrier();
  }
}

// ---------------- GEMM B: P[kz] = h[T][EH] @ woT2[D][EH]^T (split-K 8) ----------------
__global__ void __launch_bounds__(512, 2)
gemm_out_kernel(const u16* __restrict__ hb, const u16* __restrict__ woT2,
                float* __restrict__ P) {
  __shared__ u16 lds[65536];

  const int bid = blockIdx.x;          // 256 wgs
  const int wg = (bid & 7) * 32 + (bid >> 3);
  const int kz = wg >> 5;              // 0..7, one per XCD
  const int rr = wg & 31;
  const int nt = rr >> 3;              // 0..3 (D tiles of 256)
  const int mt = rr & 7;               // 0..7 (token tiles of 256)

  const int tid = threadIdx.x;
  const int lane = tid & 63;
  const int wave = tid >> 6;
  const int wm = wave >> 2, wn = wave & 3;
  const int l15 = lane & 15, lkq = lane >> 4;

  const int Am0 = mt * 256;
  const int Bn0 = nt * 256;
  const int kbase = kz * (KTOT / NSPLIT);   // 4096 per split

  f32x4 acc[8][4] = {};
  gemm_loop8<KTOT>(hb, woT2, Am0, Bn0, kbase, (KTOT / NSPLIT) / 64, lds, tid, acc);

  float* Pp = P + (size_t)kz * (T_TOK * DDIM);
#pragma unroll
  for (int a = 0; a < 8; ++a) {
#pragma unroll
    for (int r = 0; r < 4; ++r) {
      const int t = Am0 + wm * 128 + a * 16 + lkq * 4 + r;
#pragma unroll
      for (int nf = 0; nf < 4; ++nf)
        Pp[(size_t)t * DDIM + Bn0 + wn * 64 + nf * 16 + l15] = acc[a][nf][r];
    }
  }
}

// ---------------- final: out = sum of NSPLIT partials ----------------
__global__ void reduce_out_kernel(const float* __restrict__ P, float* __restrict__ out) {
  int i = blockIdx.x * 256 + threadIdx.x;
  float4 a = ((const float4*)P)[i];
#pragma unroll
  for (int s = 1; s < NSPLIT; ++s) {
    float4 b = ((const float4*)P)[i + s * (T_TOK * DDIM / 4)];
    a.x += b.x; a.y += b.y; a.z += b.z; a.w += b.w;
  }
  ((float4*)out)[i] = a;
}

extern "C" void kernel_launch(void* const* d_in, const int* in_sizes, int n_in,
                              void* d_out, int out_size, void* d_ws, size_t ws_size,
                              hipStream_t stream) {
  const float* tokens = (const float*)d_in[0];
  const float* disp   = (const float*)d_in[1];
  const float* comb   = (const float*)d_in[2];
  const float* Wg     = (const float*)d_in[3];
  const float* Wv     = (const float*)d_in[4];
  const float* Wo     = (const float*)d_in[5];
  const float* scale  = (const float*)d_in[6];
  float* out = (float*)d_out;

  char* ws = (char*)d_ws;
  const size_t MB = 1024 * 1024;
  u16* xb    = (u16*)(ws);              // 4 MB   [T][D] bf16
  u16* wgvT  = (u16*)(ws + 4   * MB);   // 128 MB [E][8192][D] interleaved g/v
  u16* woT2  = (u16*)(ws + 132 * MB);   // 64 MB  [D][E*H]
  u16* hbuf  = (u16*)(ws + 196 * MB);   // 128 MB [T][E*H]
  float* P   = (float*)(ws + 324 * MB); // 64 MB  NSPLIT x [T][D] fp32

  prep_all_kernel<<<25600, 256, 0, stream>>>(tokens, xb, Wg, Wv, Wo, wgvT, woT2);
  gemm_gv_kernel<<<4096, 256, 0, stream>>>(xb, wgvT, disp, comb, scale, hbuf);
  gemm_out_kernel<<<256, 512, 0, stream>>>(hbuf, woT2, P);
  reduce_out_kernel<<<2048, 256, 0, stream>>>(P, out);
}

// Round 17
// 506.411 us; speedup vs baseline: 7.5104x; 1.0025x over previous
//
#include <hip/hip_runtime.h>
#include <math.h>

#define T_TOK 2048
#define DDIM 1024
#define HDIM 4096
#define NEXP 8
#define NPRIME 8192            // 2*HDIM interleaved g/v cols per expert
#define KTOT (NEXP * HDIM)     // 32768
#define NSPLIT 8

typedef unsigned short u16;
typedef __attribute__((ext_vector_type(4))) float f32x4;
typedef __attribute__((ext_vector_type(8))) __bf16 bf16x8;
typedef __attribute__((ext_vector_type(8))) unsigned short u16x8;
typedef __attribute__((ext_vector_type(4))) unsigned short u16x4;

__device__ __forceinline__ u16 f2bf(float f) {
  unsigned int u = __builtin_bit_cast(unsigned int, f);
  u += 0x7fffu + ((u >> 16) & 1u);   // round-to-nearest-even
  return (u16)(u >> 16);
}

// tanh-form gelu via hardware exp2/rcp. Verified R14/R15: absmax 3.8e-5.
__device__ __forceinline__ float fast_gelu(float g) {
  float g2 = g * g;
  float y  = g * (0.7978845608f + 0.0356774081f * g2);  // sqrt(2/pi)*(g+0.044715 g^3)
  float e  = __builtin_amdgcn_exp2f(2.8853901817f * y); // e^(2y)
  float t  = 1.0f - 2.0f * __builtin_amdgcn_rcpf(1.0f + e);
  return 0.5f * g * (1.0f + t);
}

__device__ __forceinline__ void stage16(const u16* g, u16* l) {
  __builtin_amdgcn_global_load_lds((__attribute__((address_space(1))) void*)g,
                                   (__attribute__((address_space(3))) void*)l,
                                   16, 0, 0);
}

// ---------------- prep (merged): x cvt + all-expert weight transpose ----------------
__global__ void prep_all_kernel(const float* __restrict__ x, u16* __restrict__ xb,
                                const float* __restrict__ Wg,
                                const float* __restrict__ Wv,
                                const float* __restrict__ Wo,
                                u16* __restrict__ wgvT, u16* __restrict__ woT2) {
  const int tid = threadIdx.x;
  int bid = blockIdx.x;
  if (bid < 1024) {
    int i = (bid * 256 + tid) * 8;
    float4 a = *(const float4*)(x + i);
    float4 b = *(const float4*)(x + i + 4);
    u16x8 o;
    o[0] = f2bf(a.x); o[1] = f2bf(a.y); o[2] = f2bf(a.z); o[3] = f2bf(a.w);
    o[4] = f2bf(b.x); o[5] = f2bf(b.y); o[6] = f2bf(b.z); o[7] = f2bf(b.w);
    *(u16x8*)(xb + i) = o;
    return;
  }
  bid -= 1024;                          // 24576 = 8e * 3mat * 1024 tiles
  __shared__ float lds[64][65];
  const int e = bid / 3072;
  const int r = bid % 3072;
  const int which = r >> 10;            // 0=Wg 1=Wv 2=Wo
  const int tt = r & 1023;
  const float* src; int R, C;
  if (which == 2) { src = Wo + (size_t)e * HDIM * DDIM; R = HDIM; C = DDIM; }
  else            { src = (which ? Wv : Wg) + (size_t)e * DDIM * HDIM; R = DDIM; C = HDIM; }
  const int nrt = R >> 6;
  const int r0 = (tt % nrt) << 6, c0 = (tt / nrt) << 6;
#pragma unroll
  for (int i = 0; i < 4; ++i) {
    int f4 = tid + 256 * i;
    int row = f4 >> 4, c4 = (f4 & 15) << 2;
    float4 v = *(const float4*)(src + (size_t)(r0 + row) * C + c0 + c4);
    lds[row][c4] = v.x; lds[row][c4 + 1] = v.y; lds[row][c4 + 2] = v.z; lds[row][c4 + 3] = v.w;
  }
  __syncthreads();
#pragma unroll
  for (int i = 0; i < 4; ++i) {
    int f4 = tid + 256 * i;
    int cc = f4 >> 4, r4 = (f4 & 15) << 2;
    u16x4 o;
    o[0] = f2bf(lds[r4][cc]);     o[1] = f2bf(lds[r4 + 1][cc]);
    o[2] = f2bf(lds[r4 + 2][cc]); o[3] = f2bf(lds[r4 + 3][cc]);
    u16* dst;
    if (which == 2) {
      dst = woT2 + (size_t)(c0 + cc) * KTOT + e * HDIM + r0 + r4;
    } else {
      int h = c0 + cc;
      int rowp = ((h >> 4) << 5) + which * 16 + (h & 15);
      dst = wgvT + (size_t)e * NPRIME * DDIM + (size_t)rowp * DDIM + r0 + r4;
    }
    *(u16x4*)dst = o;
  }
}

// =================================================================
// gemm_loop4 (gv): BM=256, BN=128, BK=64, 4 waves, 256 thr, 64 KB LDS
// -> 2 blocks/CU (best measured gv config, R13/R14, unchanged).
// =================================================================
template<int KS>
__device__ __forceinline__ void gemm_loop4(const u16* Ab, const u16* Bb,
                                           int Am0, int Bn0, int kbase, int NT,
                                           u16* lds, int tid, f32x4 (&acc)[8][4]) {
  const int lane = tid & 63;
  const int wave = tid >> 6;            // 0..3
  const int wm = wave >> 1, wn = wave & 1;
  const int l15 = lane & 15, lkq = lane >> 4;

  const int sl = tid & 7, r0 = tid >> 3;          // r0 0..31
  const int slx = (sl ^ (r0 & 7)) << 3;
  const u16* pA = Ab + (size_t)(Am0 + r0) * KS + kbase + slx;
  const u16* pB = Bb + (size_t)(Bn0 + r0) * KS + kbase + slx;
  const int dA0 = r0 * 64 + sl * 8;
  const int dB0 = r0 * 64 + sl * 8;

  const int swz0 = (lkq ^ (l15 & 7)) << 3;
  const int swz1 = ((4 | lkq) ^ (l15 & 7)) << 3;
  const int arow = (wm * 128 + l15) * 64;
  const int brow = (wn * 64 + l15) * 64;
  const int a0 = arow + swz0, a1 = arow + swz1;
  const int b0 = brow + swz0, b1 = brow + swz1;

#pragma unroll
  for (int i = 0; i < 8; ++i) stage16(pA + (size_t)(i * 32) * KS, lds + dA0 + i * 2048);
#pragma unroll
  for (int i = 0; i < 4; ++i) stage16(pB + (size_t)(i * 32) * KS, lds + 16384 + dB0 + i * 2048);
  asm volatile("s_waitcnt vmcnt(0)" ::: "memory");
  __builtin_amdgcn_s_barrier();

#pragma unroll 1
  for (int t = 0; t < NT; ++t) {
    const int bs = 16384 + ((t & 1) << 13);
    const int bn = 16384 + (((t + 1) & 1) << 13);
    const int tp1 = (t + 1 < NT) ? t + 1 : NT - 1;
    const size_t kn = (size_t)(tp1 << 6);
    bf16x8 af[8][2], bfr[4];

#pragma unroll
    for (int mf = 0; mf < 8; ++mf) {
      af[mf][0] = *(const bf16x8*)(lds + a0 + mf * 1024);
      af[mf][1] = *(const bf16x8*)(lds + a1 + mf * 1024);
    }
#pragma unroll
    for (int nf = 0; nf < 4; ++nf) bfr[nf] = *(const bf16x8*)(lds + bs + b0 + nf * 1024);
    asm volatile("s_waitcnt lgkmcnt(0)" ::: "memory");
    __builtin_amdgcn_s_barrier();

#pragma unroll
    for (int i = 0; i < 8; ++i) stage16(pA + (size_t)(i * 32) * KS + kn, lds + dA0 + i * 2048);
#pragma unroll
    for (int i = 0; i < 4; ++i) stage16(pB + (size_t)(i * 32) * KS + kn, lds + bn + dB0 + i * 2048);
    __builtin_amdgcn_sched_barrier(0);

    __builtin_amdgcn_s_setprio(1);
#pragma unroll
    for (int mf = 0; mf < 8; ++mf)
#pragma unroll
      for (int nf = 0; nf < 4; ++nf)
        acc[mf][nf] = __builtin_amdgcn_mfma_f32_16x16x32_bf16(af[mf][0], bfr[nf], acc[mf][nf], 0, 0, 0);
    __builtin_amdgcn_s_setprio(0);

#pragma unroll
    for (int nf = 0; nf < 4; ++nf) bfr[nf] = *(const bf16x8*)(lds + bs + b1 + nf * 1024);
    __builtin_amdgcn_s_setprio(1);
#pragma unroll
    for (int mf = 0; mf < 8; ++mf)
#pragma unroll
      for (int nf = 0; nf < 4; ++nf)
        acc[mf][nf] = __builtin_amdgcn_mfma_f32_16x16x32_bf16(af[mf][1], bfr[nf], acc[mf][nf], 0, 0, 0);
    __builtin_amdgcn_s_setprio(0);

    asm volatile("s_waitcnt vmcnt(0)" ::: "memory");
    __builtin_amdgcn_s_barrier();
  }
}

// ---------------- GEMM A: h = (gelu(x@Wg) * (x@Wv)) * scale * cw ----------------
__global__ void __launch_bounds__(256, 2)
gemm_gv_kernel(const u16* __restrict__ xb, const u16* __restrict__ wgvT,
               const float* __restrict__ disp, const float* __restrict__ comb,
               const float* __restrict__ scale, u16* __restrict__ h) {
  __shared__ u16 lds[32768];   // 64 KB -> 2 blocks/CU

  const int bid = blockIdx.x;
  const int wg = (bid & 7) * 512 + (bid >> 3);
  const int e  = wg >> 9;
  const int rr = wg & 511;
  const int nt = rr >> 3;          // 0..63 (N' tiles of 128)
  const int mt = rr & 7;           // 0..7  (M tiles of 256)

  const int tid = threadIdx.x;
  const int lane = tid & 63;
  const int wave = tid >> 6;
  const int wm = wave >> 1, wn = wave & 1;
  const int l15 = lane & 15, lkq = lane >> 4;

  const u16* Bb = wgvT + (size_t)e * NPRIME * DDIM;
  const int Am0 = mt * 256;
  const int Bn0 = nt * 128;

  f32x4 acc[8][4] = {};
  gemm_loop4<DDIM>(xb, Bb, Am0, Bn0, 0, DDIM / 64, lds, tid, acc);

  const float s_e = scale[e];
  const int hbase = nt * 64 + wn * 32;   // H-col base within expert
#pragma unroll
  for (int a = 0; a < 8; ++a) {
#pragma unroll
    for (int r = 0; r < 4; ++r) {
      const int t = Am0 + wm * 128 + a * 16 + lkq * 4 + r;
      const float dv = disp[t * NEXP + e];
      const float cv = comb[t * NEXP + e];
      const float s = (dv > 0.0f) ? cv * s_e : 0.0f;
#pragma unroll
      for (int jj = 0; jj < 2; ++jj) {
        const float g = acc[a][2 * jj][r];
        const float v = acc[a][2 * jj + 1][r];
        h[(size_t)t * KTOT + e * HDIM + hbase + jj * 16 + l15] = f2bf(fast_gelu(g) * v * s);
      }
    }
  }
}

// =================================================================
// gemm_loop8 (out, R16): BM=256, BN=256, BK=64, 8 waves, 512 thr,
// 128 KB LDS, quarter-replacement staging with 2-tile lead.
// Single barrier per phase + counted vmcnt(10) (never 0 in loop)
// + pre-barrier lgkmcnt(0) (discharges the WAR edge that R9 paid two
// barriers for) + no sched_barrier pins.
// Ledger (units of 2 loads, steady state):
//  p0: issue SA1(t+1); q=12; vmcnt(10) drains SB1(t)   [B23(t) for p1]
//  p1: issue SA0(t+2); q=12; vmcnt(10) drains SA1(t)   [A-h1(t) for p2]
//  p2: issue SB0(t+2); q=12; no wait
//  p3: issue SB1(t+2); q=14; vmcnt(10) drains SA0,SB0(t+1) [for p0(t+1)]
// WAR: every staged region's readers lgkm-drained before the preceding
// barrier (reads + lgkmcnt(0) precede BAR; stage issued after BAR).
// Tail: tp1/tp2 clamp to NT-1 -> value-identical re-stage (benign).
// =================================================================
template<int KS>
__device__ __forceinline__ void gemm_loop8(const u16* Ab, const u16* Bb,
                                           int Am0, int Bn0, int kbase, int NT,
                                           u16* lds, int tid, f32x4 (&acc)[8][4]) {
  const int lane = tid & 63;
  const int wave = tid >> 6;
  const int wm = wave >> 2, wn = wave & 3;
  const int l15 = lane & 15, lkq = lane >> 4;

  const int sl = tid & 7, rw = tid >> 3;
  const int slx = (sl ^ (rw & 7)) << 3;
  const int rb = (rw & 31) + ((rw >> 5) << 6);
  const u16* pA = Ab + (size_t)(Am0 + rw) * KS + kbase + slx;
  const u16* pB = Bb + (size_t)(Bn0 + rb) * KS + kbase + slx;
  const int dA = rw * 64 + sl * 8;
  const int dB = 16384 + rb * 64 + sl * 8;

  auto slot = [&](int t) -> u16* { return lds + (t & 1) * 32768; };
  auto SA0 = [&](int t) { u16* sp = slot(t); const int k = t << 6;
    stage16(pA + k, sp + dA);
    stage16(pA + (size_t)128 * KS + k, sp + dA + 8192); };
  auto SA1 = [&](int t) { u16* sp = slot(t); const int k = t << 6;
    stage16(pA + (size_t)64 * KS + k, sp + dA + 4096);
    stage16(pA + (size_t)192 * KS + k, sp + dA + 12288); };
  auto SB0 = [&](int t) { u16* sp = slot(t); const int k = t << 6;
    stage16(pB + k, sp + dB);
    stage16(pB + (size_t)128 * KS + k, sp + dB + 8192); };
  auto SB1 = [&](int t) { u16* sp = slot(t); const int k = t << 6;
    stage16(pB + (size_t)32 * KS + k, sp + dB + 2048);
    stage16(pB + (size_t)160 * KS + k, sp + dB + 10240); };

  const int swz0 = (lkq ^ (l15 & 7)) << 3;
  const int swz1 = ((4 | lkq) ^ (l15 & 7)) << 3;
  const int arow = (wm * 128 + l15) * 64;
  const int brow = 16384 + (wn * 64 + l15) * 64;
  const int a0 = arow + swz0, a1 = arow + swz1;
  const int b0 = brow + swz0, b1 = brow + swz1;

  SA0(0); SB0(0); SB1(0); SA1(0);
  SA0(1); SB0(1); SB1(1);
  asm volatile("s_waitcnt vmcnt(10)" ::: "memory");
  __builtin_amdgcn_s_barrier();

#pragma unroll 1
  for (int t = 0; t < NT; ++t) {
    const u16* s = slot(t);
    const int tp1 = (t + 1 < NT) ? t + 1 : NT - 1;
    const int tp2 = (t + 2 < NT) ? t + 2 : NT - 1;
    bf16x8 af[4][2], bfr[4][2];

    // ---- p0: read A-h0 + B-n01 ; SA1(t+1) ; vmcnt(10) ; BAR ; MFMA m0-3 x n01
#pragma unroll
    for (int mf = 0; mf < 4; ++mf) {
      af[mf][0] = *(const bf16x8*)(s + a0 + mf * 1024);
      af[mf][1] = *(const bf16x8*)(s + a1 + mf * 1024);
    }
#pragma unroll
    for (int nf = 0; nf < 2; ++nf) {
      bfr[nf][0] = *(const bf16x8*)(s + b0 + nf * 1024);
      bfr[nf][1] = *(const bf16x8*)(s + b1 + nf * 1024);
    }
    asm volatile("s_waitcnt lgkmcnt(0)" ::: "memory");
    SA1(tp1);
    asm volatile("s_waitcnt vmcnt(10)" ::: "memory");
    __builtin_amdgcn_s_barrier();
    __builtin_amdgcn_s_setprio(1);
#pragma unroll
    for (int ks = 0; ks < 2; ++ks)
#pragma unroll
      for (int mf = 0; mf < 4; ++mf)
#pragma unroll
        for (int nf = 0; nf < 2; ++nf)
          acc[mf][nf] = __builtin_amdgcn_mfma_f32_16x16x32_bf16(af[mf][ks], bfr[nf][ks], acc[mf][nf], 0, 0, 0);
    __builtin_amdgcn_s_setprio(0);

    // ---- p1: read B-n23 ; SA0(t+2) ; vmcnt(10) ; BAR ; MFMA m0-3 x n23
#pragma unroll
    for (int nf = 2; nf < 4; ++nf) {
      bfr[nf][0] = *(const bf16x8*)(s + b0 + nf * 1024);
      bfr[nf][1] = *(const bf16x8*)(s + b1 + nf * 1024);
    }
    asm volatile("s_waitcnt lgkmcnt(0)" ::: "memory");
    SA0(tp2);
    asm volatile("s_waitcnt vmcnt(10)" ::: "memory");
    __builtin_amdgcn_s_barrier();
    __builtin_amdgcn_s_setprio(1);
#pragma unroll
    for (int ks = 0; ks < 2; ++ks)
#pragma unroll
      for (int mf = 0; mf < 4; ++mf)
#pragma unroll
        for (int nf = 2; nf < 4; ++nf)
          acc[mf][nf] = __builtin_amdgcn_mfma_f32_16x16x32_bf16(af[mf][ks], bfr[nf][ks], acc[mf][nf], 0, 0, 0);
    __builtin_amdgcn_s_setprio(0);

    // ---- p2: read A-h1 ; SB0(t+2) ; BAR ; MFMA m4-7 x n01
#pragma unroll
    for (int mf = 0; mf < 4; ++mf) {
      af[mf][0] = *(const bf16x8*)(s + a0 + 4096 + mf * 1024);
      af[mf][1] = *(const bf16x8*)(s + a1 + 4096 + mf * 1024);
    }
    asm volatile("s_waitcnt lgkmcnt(0)" ::: "memory");
    SB0(tp2);
    __builtin_amdgcn_s_barrier();
    __builtin_amdgcn_s_setprio(1);
#pragma unroll
    for (int ks = 0; ks < 2; ++ks)
#pragma unroll
      for (int mf = 0; mf < 4; ++mf)
#pragma unroll
        for (int nf = 0; nf < 2; ++nf)
          acc[4 + mf][nf] = __builtin_amdgcn_mfma_f32_16x16x32_bf16(af[mf][ks], bfr[nf][ks], acc[4 + mf][nf], 0, 0, 0);
    __builtin_amdgcn_s_setprio(0);

    // ---- p3: SB1(t+2) ; vmcnt(10) ; BAR ; MFMA m4-7 x n23
    SB1(tp2);
    asm volatile("s_waitcnt vmcnt(10)" ::: "memory");
    __builtin_amdgcn_s_barrier();
    __builtin_amdgcn_s_setprio(1);
#pragma unroll
    for (int ks = 0; ks < 2; ++ks)
#pragma unroll
      for (int mf = 0; mf < 4; ++mf)
#pragma unroll
        for (int nf = 2; nf < 4; ++nf)
          acc[4 + mf][nf] = __builtin_amdgcn_mfma_f32_16x16x32_bf16(af[mf][ks], bfr[nf][ks], acc[4 + mf][nf], 0, 0, 0);
    __builtin_amdgcn_s_setprio(0);
  }
}

// ---------------- GEMM B: P[kz] = h[T][EH] @ woT2[D][EH]^T (split-K 8) ----------------
__global__ void __launch_bounds__(512, 2)
gemm_out_kernel(const u16* __restrict__ hb, const u16* __restrict__ woT2,
                float* __restrict__ P) {
  __shared__ u16 lds[65536];

  const int bid = blockIdx.x;          // 256 wgs
  const int wg = (bid & 7) * 32 + (bid >> 3);
  const int kz = wg >> 5;              // 0..7, one per XCD
  const int rr = wg & 31;
  const int nt = rr >> 3;              // 0..3 (D tiles of 256)
  const int mt = rr & 7;               // 0..7 (token tiles of 256)

  const int tid = threadIdx.x;
  const int lane = tid & 63;
  const int wave = tid >> 6;
  const int wm = wave >> 2, wn = wave & 3;
  const int l15 = lane & 15, lkq = lane >> 4;

  const int Am0 = mt * 256;
  const int Bn0 = nt * 256;
  const int kbase = kz * (KTOT / NSPLIT);   // 4096 per split

  f32x4 acc[8][4] = {};
  gemm_loop8<KTOT>(hb, woT2, Am0, Bn0, kbase, (KTOT / NSPLIT) / 64, lds, tid, acc);

  float* Pp = P + (size_t)kz * (T_TOK * DDIM);
#pragma unroll
  for (int a = 0; a < 8; ++a) {
#pragma unroll
    for (int r = 0; r < 4; ++r) {
      const int t = Am0 + wm * 128 + a * 16 + lkq * 4 + r;
#pragma unroll
      for (int nf = 0; nf < 4; ++nf)
        Pp[(size_t)t * DDIM + Bn0 + wn * 64 + nf * 16 + l15] = acc[a][nf][r];
    }
  }
}

// ---------------- final: out = sum of NSPLIT partials ----------------
__global__ void reduce_out_kernel(const float* __restrict__ P, float* __restrict__ out) {
  int i = blockIdx.x * 256 + threadIdx.x;
  float4 a = ((const float4*)P)[i];
#pragma unroll
  for (int s = 1; s < NSPLIT; ++s) {
    float4 b = ((const float4*)P)[i + s * (T_TOK * DDIM / 4)];
    a.x += b.x; a.y += b.y; a.z += b.z; a.w += b.w;
  }
  ((float4*)out)[i] = a;
}

extern "C" void kernel_launch(void* const* d_in, const int* in_sizes, int n_in,
                              void* d_out, int out_size, void* d_ws, size_t ws_size,
                              hipStream_t stream) {
  const float* tokens = (const float*)d_in[0];
  const float* disp   = (const float*)d_in[1];
  const float* comb   = (const float*)d_in[2];
  const float* Wg     = (const float*)d_in[3];
  const float* Wv     = (const float*)d_in[4];
  const float* Wo     = (const float*)d_in[5];
  const float* scale  = (const float*)d_in[6];
  float* out = (float*)d_out;

  char* ws = (char*)d_ws;
  const size_t MB = 1024 * 1024;
  u16* xb    = (u16*)(ws);              // 4 MB   [T][D] bf16
  u16* wgvT  = (u16*)(ws + 4   * MB);   // 128 MB [E][8192][D] interleaved g/v
  u16* woT2  = (u16*)(ws + 132 * MB);   // 64 MB  [D][E*H]
  u16* hbuf  = (u16*)(ws + 196 * MB);   // 128 MB [T][E*H]
  float* P   = (float*)(ws + 324 * MB); // 64 MB  NSPLIT x [T][D] fp32

  prep_all_kernel<<<25600, 256, 0, stream>>>(tokens, xb, Wg, Wv, Wo, wgvT, woT2);
  gemm_gv_kernel<<<4096, 256, 0, stream>>>(xb, wgvT, disp, comb, scale, hbuf);
  gemm_out_kernel<<<256, 512, 0, stream>>>(hbuf, woT2, P);
  reduce_out_kernel<<<2048, 256, 0, stream>>>(P, out);
}